// Round 2
// baseline (933.348 us; speedup 1.0000x reference)
//
#include <hip/hip_runtime.h>
#include <math.h>

#define BATCH 8
#define SSIZE 1048576   // 128*128*64
#define KT 16

// R7 (resubmit R8): gram kernels rewritten with MFMA bf16 split-precision
// (hi+lo, 3 products per real matmul => ~8e-6 rel err). mix/score/zero
// unchanged (proven R5/R6). Static re-audit round: fragment layouts, swizzle
// write/read consistency, alignment, occupancy all verified by hand.

typedef short sh8 __attribute__((ext_vector_type(8)));
typedef float f32x4 __attribute__((ext_vector_type(4)));

#define MFMA16(a, b, c) __builtin_amdgcn_mfma_f32_16x16x32_bf16((a), (b), (c), 0, 0, 0)

__device__ __forceinline__ unsigned short bf_rne(float x) {
    unsigned u = __float_as_uint(x);
    unsigned r = u + 0x7fffu + ((u >> 16) & 1u);
    return (unsigned short)(r >> 16);
}

// split x into hi + lo bf16 (both RNE)
__device__ __forceinline__ void split1(float x, unsigned short &h, unsigned short &l) {
    h = bf_rne(x);
    float hf = __uint_as_float((unsigned)h << 16);
    l = bf_rne(x - hf);
}

__device__ __forceinline__ float f4c(const float4 &v, int c) {
    return c == 0 ? v.x : c == 1 ? v.y : c == 2 ? v.z : v.w;
}

// fragment load from a bf16 plane [rows][32 k] with XOR swizzle ((row&3)<<3 ushorts)
__device__ __forceinline__ sh8 ldfrag(const unsigned short *pl, int row, int kg) {
    const int idx = (row * 32 + kg * 8) ^ ((row & 3) << 3);
    return *(const sh8 *)(pl + idx);
}

// ---------------- zero kernel (graph-capture-safe G clear) ----------------
__global__ void zero_kernel(float* __restrict__ p, int n) {
    int i = blockIdx.x * blockDim.x + threadIdx.x;
    if (i < n) p[i] = 0.0f;
}

// =====================================================================
// gram_mfma (modes 0/1, d=128): G = u u^T (no conj), symmetric.
// 3 tiles of 64x64: 0=(0,0), 1=(0,64)+mirror, 2=(64,64).
// Per k-step(32): stage 64 rows x 32 k per side as 4 bf16 planes
// (rH,rL,iH,iL), swizzled; 4 waves each own a 32x32 quadrant =
// 2x2 subtile-pairs x 12 mfma_16x16x32 (split-precision complex).
// =====================================================================
template<int SI_, int KL2_, int SKH_>
__global__ __launch_bounds__(256, 3)
void gram_mfma_kernel(const float* __restrict__ srcR, const float* __restrict__ srcI,
                      float* __restrict__ G, int kPerBlock)
{
    const int tile = blockIdx.x;             // 0,1,2
    const int it = (tile == 2) ? 64 : 0;
    const int jt = (tile == 0) ? 0 : 64;
    const bool diag = (it == jt);
    const int b  = blockIdx.z;
    const int k0 = blockIdx.y * kPerBlock;

    const int t    = threadIdx.x;
    const int lane = t & 63;
    const int wave = t >> 6;          // 0..3
    const int wr = wave & 1, wc = wave >> 1;

    __shared__ unsigned short SA[4][2048];   // planes rH,rL,iH,iL  [64 rows][32 k]
    __shared__ unsigned short SB[4][2048];

    const sh8 SGN = {(short)0x8000, (short)0x8000, (short)0x8000, (short)0x8000,
                     (short)0x8000, (short)0x8000, (short)0x8000, (short)0x8000};

    f32x4 gr[2][2], gi[2][2];
    const f32x4 z4 = {0.f, 0.f, 0.f, 0.f};
    #pragma unroll
    for (int x = 0; x < 2; x++)
        #pragma unroll
        for (int y = 0; y < 2; y++) { gr[x][y] = z4; gi[x][y] = z4; }

    const size_t boff = (size_t)b * SSIZE;
    const int nT = kPerBlock >> 5;

    // staging map: 8 k-quads x 32 row2 (rows row2, row2+32)
    const int kq   = t & 7;
    const int row2 = t >> 3;

    const int frow = lane & 15;
    const int kg   = lane >> 4;

    #define GADDR(ii, k) (boff + (size_t)(ii) * SI_ + \
        (size_t)((k) >> KL2_) * SKH_ + (size_t)((k) & ((1 << KL2_) - 1)))

    for (int kt = 0; kt < nT; kt++) {
        const int kb = k0 + kt * 32;
        #pragma unroll
        for (int m = 0; m < 2; m++) {
            const int row = row2 + 32 * m;
            const int idx = (row * 32 + kq * 4) ^ ((row & 3) << 3);
            {
                const size_t off = GADDR(it + row, kb + kq * 4);
                const float4 R = *(const float4*)(srcR + off);
                const float4 I = *(const float4*)(srcI + off);
                ushort4 rh, rl, ih, il;
                split1(R.x, rh.x, rl.x); split1(R.y, rh.y, rl.y);
                split1(R.z, rh.z, rl.z); split1(R.w, rh.w, rl.w);
                split1(I.x, ih.x, il.x); split1(I.y, ih.y, il.y);
                split1(I.z, ih.z, il.z); split1(I.w, ih.w, il.w);
                *(ushort4*)&SA[0][idx] = rh;
                *(ushort4*)&SA[1][idx] = rl;
                *(ushort4*)&SA[2][idx] = ih;
                *(ushort4*)&SA[3][idx] = il;
            }
            if (!diag) {
                const size_t off = GADDR(jt + row, kb + kq * 4);
                const float4 R = *(const float4*)(srcR + off);
                const float4 I = *(const float4*)(srcI + off);
                ushort4 rh, rl, ih, il;
                split1(R.x, rh.x, rl.x); split1(R.y, rh.y, rl.y);
                split1(R.z, rh.z, rl.z); split1(R.w, rh.w, rl.w);
                split1(I.x, ih.x, il.x); split1(I.y, ih.y, il.y);
                split1(I.z, ih.z, il.z); split1(I.w, il.w, il.w);
                // NOTE: the line above must be split1(I.w, ih.w, il.w) — kept correct below
                split1(I.w, ih.w, il.w);
                *(ushort4*)&SB[0][idx] = rh;
                *(ushort4*)&SB[1][idx] = rl;
                *(ushort4*)&SB[2][idx] = ih;
                *(ushort4*)&SB[3][idx] = il;
            }
        }
        __syncthreads();

        unsigned short (*BP)[2048] = diag ? SA : SB;

        sh8 a[2][4], na[2][2], bfr[2][4];
        #pragma unroll
        for (int s = 0; s < 2; s++) {
            const int row = wr * 32 + s * 16 + frow;
            #pragma unroll
            for (int p = 0; p < 4; p++) a[s][p] = ldfrag(&SA[p][0], row, kg);
            na[s][0] = a[s][2] ^ SGN;
            na[s][1] = a[s][3] ^ SGN;
        }
        #pragma unroll
        for (int s = 0; s < 2; s++) {
            const int row = wc * 32 + s * 16 + frow;
            #pragma unroll
            for (int p = 0; p < 4; p++) bfr[s][p] = ldfrag(&BP[p][0], row, kg);
        }

        #pragma unroll
        for (int sr = 0; sr < 2; sr++) {
            #pragma unroll
            for (int sc = 0; sc < 2; sc++) {
                f32x4 r = gr[sr][sc], q = gi[sr][sc];
                // Gr = Ar Br^T - Ai Bi^T  (split: HH + HL + LH)
                r = MFMA16(a[sr][0],  bfr[sc][0], r);
                r = MFMA16(a[sr][0],  bfr[sc][1], r);
                r = MFMA16(a[sr][1],  bfr[sc][0], r);
                r = MFMA16(na[sr][0], bfr[sc][2], r);
                r = MFMA16(na[sr][0], bfr[sc][3], r);
                r = MFMA16(na[sr][1], bfr[sc][2], r);
                // Gi = Ar Bi^T + Ai Br^T
                q = MFMA16(a[sr][0],  bfr[sc][2], q);
                q = MFMA16(a[sr][0],  bfr[sc][3], q);
                q = MFMA16(a[sr][1],  bfr[sc][2], q);
                q = MFMA16(a[sr][2],  bfr[sc][0], q);
                q = MFMA16(a[sr][2],  bfr[sc][1], q);
                q = MFMA16(a[sr][3],  bfr[sc][0], q);
                gr[sr][sc] = r; gi[sr][sc] = q;
            }
        }
        __syncthreads();
    }
    #undef GADDR

    float* Gb = G + (size_t)b * 128 * 128 * 2;
    const int rb   = (lane >> 4) * 4;
    const int jcol = lane & 15;
    #pragma unroll
    for (int sr = 0; sr < 2; sr++)
        #pragma unroll
        for (int sc = 0; sc < 2; sc++)
            #pragma unroll
            for (int r = 0; r < 4; r++) {
                const int i = it + wr * 32 + sr * 16 + rb + r;
                const int j = jt + wc * 32 + sc * 16 + jcol;
                const float vr = gr[sr][sc][r], vi = gi[sr][sc][r];
                atomicAdd(&Gb[(i * 128 + j) * 2 + 0], vr);
                atomicAdd(&Gb[(i * 128 + j) * 2 + 1], vi);
                if (!diag) {   // mirror: G[j][i] = G[i][j]
                    atomicAdd(&Gb[(j * 128 + i) * 2 + 0], vr);
                    atomicAdd(&Gb[(j * 128 + i) * 2 + 1], vi);
                }
            }
}

// =====================================================================
// gram64_mfma (mode 2, d=64): u(b,i,k) = boff + i + (k&127)*64 + (k>>7)*8192.
// i is contiguous => transposed staging (gather 2 k per i, b32 writes).
// Full 64x64 output per block, 4 waves x 32x32 quadrants.
// =====================================================================
__global__ __launch_bounds__(256, 3)
void gram64_mfma_kernel(const float* __restrict__ srcR, const float* __restrict__ srcI,
                        float* __restrict__ G, int kPerBlock)
{
    const int b  = blockIdx.y;
    const int k0 = blockIdx.x * kPerBlock;

    const int t    = threadIdx.x;
    const int lane = t & 63;
    const int wave = t >> 6;
    const int wr = wave & 1, wc = wave >> 1;

    __shared__ unsigned short SA[4][2048];   // planes [64 i][32 k]

    const sh8 SGN = {(short)0x8000, (short)0x8000, (short)0x8000, (short)0x8000,
                     (short)0x8000, (short)0x8000, (short)0x8000, (short)0x8000};

    f32x4 gr[2][2], gi[2][2];
    const f32x4 z4 = {0.f, 0.f, 0.f, 0.f};
    #pragma unroll
    for (int x = 0; x < 2; x++)
        #pragma unroll
        for (int y = 0; y < 2; y++) { gr[x][y] = z4; gi[x][y] = z4; }

    const size_t boff = (size_t)b * SSIZE;
    const int nT = kPerBlock >> 5;

    // staging map: kp-major, 64B-chunk coalesced loads
    const int kp = t & 15;        // k = 2kp, 2kp+1 within tile
    const int i0 = (t >> 4) * 4;  // i quad

    const int frow = lane & 15;
    const int kg   = lane >> 4;

    for (int kt = 0; kt < nT; kt++) {
        const int kb = k0 + kt * 32;
        const int ke = kb + 2 * kp;
        const int ko = ke + 1;
        const size_t offE = boff + (size_t)(ke & 127) * 64 + (size_t)(ke >> 7) * 8192 + i0;
        const size_t offO = boff + (size_t)(ko & 127) * 64 + (size_t)(ko >> 7) * 8192 + i0;
        const float4 R0 = *(const float4*)(srcR + offE);
        const float4 I0 = *(const float4*)(srcI + offE);
        const float4 R1 = *(const float4*)(srcR + offO);
        const float4 I1 = *(const float4*)(srcI + offO);
        const int kw = 2 * kp;
        #pragma unroll
        for (int c = 0; c < 4; c++) {
            const int i   = i0 + c;
            const int idx = (i * 32 + kw) ^ ((i & 3) << 3);
            unsigned short h0, l0, h1, l1;
            split1(f4c(R0, c), h0, l0);
            split1(f4c(R1, c), h1, l1);
            *(ushort2*)&SA[0][idx] = make_ushort2(h0, h1);
            *(ushort2*)&SA[1][idx] = make_ushort2(l0, l1);
            split1(f4c(I0, c), h0, l0);
            split1(f4c(I1, c), h1, l1);
            *(ushort2*)&SA[2][idx] = make_ushort2(h0, h1);
            *(ushort2*)&SA[3][idx] = make_ushort2(l0, l1);
        }
        __syncthreads();

        sh8 a[2][4], na[2][2], bfr[2][4];
        #pragma unroll
        for (int s = 0; s < 2; s++) {
            const int row = wr * 32 + s * 16 + frow;
            #pragma unroll
            for (int p = 0; p < 4; p++) a[s][p] = ldfrag(&SA[p][0], row, kg);
            na[s][0] = a[s][2] ^ SGN;
            na[s][1] = a[s][3] ^ SGN;
        }
        #pragma unroll
        for (int s = 0; s < 2; s++) {
            const int row = wc * 32 + s * 16 + frow;
            #pragma unroll
            for (int p = 0; p < 4; p++) bfr[s][p] = ldfrag(&SA[p][0], row, kg);
        }

        #pragma unroll
        for (int sr = 0; sr < 2; sr++) {
            #pragma unroll
            for (int sc = 0; sc < 2; sc++) {
                f32x4 r = gr[sr][sc], q = gi[sr][sc];
                r = MFMA16(a[sr][0],  bfr[sc][0], r);
                r = MFMA16(a[sr][0],  bfr[sc][1], r);
                r = MFMA16(a[sr][1],  bfr[sc][0], r);
                r = MFMA16(na[sr][0], bfr[sc][2], r);
                r = MFMA16(na[sr][0], bfr[sc][3], r);
                r = MFMA16(na[sr][1], bfr[sc][2], r);
                q = MFMA16(a[sr][0],  bfr[sc][2], q);
                q = MFMA16(a[sr][0],  bfr[sc][3], q);
                q = MFMA16(a[sr][1],  bfr[sc][2], q);
                q = MFMA16(a[sr][2],  bfr[sc][0], q);
                q = MFMA16(a[sr][2],  bfr[sc][1], q);
                q = MFMA16(a[sr][3],  bfr[sc][0], q);
                gr[sr][sc] = r; gi[sr][sc] = q;
            }
        }
        __syncthreads();
    }

    float* Gb = G + (size_t)b * 64 * 64 * 2;
    const int rb   = (lane >> 4) * 4;
    const int jcol = lane & 15;
    #pragma unroll
    for (int sr = 0; sr < 2; sr++)
        #pragma unroll
        for (int sc = 0; sc < 2; sc++)
            #pragma unroll
            for (int r = 0; r < 4; r++) {
                const int i = wr * 32 + sr * 16 + rb + r;
                const int j = wc * 32 + sc * 16 + jcol;
                atomicAdd(&Gb[(i * 64 + j) * 2 + 0], gr[sr][sc][r]);
                atomicAdd(&Gb[(i * 64 + j) * 2 + 1], gi[sr][sc][r]);
            }
}

// ---------------- score/softmax/phase -> routing matrix M ----------------
__global__ __launch_bounds__(128)
void score_kernel(const float* __restrict__ G,
                  const float* __restrict__ Wre, const float* __restrict__ Wim,
                  const float* __restrict__ log_tau,
                  float2* __restrict__ Mout, int d)
{
    const int b = blockIdx.y;
    const int i = blockIdx.x;
    const int j = threadIdx.x;

    const float2* Gb = (const float2*)G + (size_t)b * d * d;

    float sre = 0.f, sim = 0.f;
    for (int l = 0; l < d; l++) {
        float wr = Wre[i * d + l];
        float wi = Wim[i * d + l];
        float2 g = Gb[l * d + j];
        sre = fmaf(wr, g.x, sre);
        sre = fmaf(-wi, g.y, sre);
        sim = fmaf(wr, g.y, sim);
        sim = fmaf(wi, g.x, sim);
    }

    float mag = sqrtf(sre * sre + sim * sim);
    float tau = fmaxf(expf(log_tau[0]), 1e-8f);
    float scale = tau * sqrtf((float)SSIZE / (float)d);
    float mval = mag / scale;

    __shared__ float red[128];
    red[j] = mval;
    __syncthreads();
    for (int s = d >> 1; s > 0; s >>= 1) {
        if (j < s) red[j] = fmaxf(red[j], red[j + s]);
        __syncthreads();
    }
    float mx = red[0];
    __syncthreads();
    float e = expf(mval - mx);
    red[j] = e;
    __syncthreads();
    for (int s = d >> 1; s > 0; s >>= 1) {
        if (j < s) red[j] += red[j + s];
        __syncthreads();
    }
    float routing = e / red[0];

    float safe = fmaxf(mag, 1e-8f);
    float pre, pim;
    if (mag > 1e-8f) { pre = sre / safe; pim = sim / safe; }
    else             { pre = 1.f;       pim = 0.f; }

    Mout[(size_t)b * d * d + i * d + j] = make_float2(routing * pre, routing * pim);
}

// =====================================================================
// mix128 (modes 0/1, d=128): dst(b,i,k) = sum_j M[b,i,j]*u(b,j,k).
// Proven R6-single-buffer fp32 version (unchanged this round).
// =====================================================================
template<int SI_, int KL2_, int SKH_>
__global__ __launch_bounds__(256)
void mix128_kernel(const float* __restrict__ srcR, const float* __restrict__ srcI,
                   const float2* __restrict__ M,
                   float* __restrict__ dstR, float* __restrict__ dstI)
{
    const int kb0 = blockIdx.x << 6;   // 64-wide k tile (aligned to KLO)
    const int it  = blockIdx.y << 6;   // 64-wide i tile
    const int b   = blockIdx.z;

    const int t  = threadIdx.x;
    const int ti = t & 15;   // i groups
    const int tj = t >> 4;   // k groups

    __shared__ float2 Ms[KT][66];   // [jj][ii]
    __shared__ float2 Us[KT][66];   // [jj][kk]

    float accr[4][4] = {{0.f}}, acci[4][4] = {{0.f}};

    const size_t boff = (size_t)b * SSIZE;
    const float2* Mb  = M + (size_t)b * 128 * 128;

    #define GADDR(jj, k) (boff + (size_t)(jj) * SI_ + \
        (size_t)((k) >> KL2_) * SKH_ + (size_t)((k) & ((1 << KL2_) - 1)))

    // staging maps
    const int mi  = t >> 2;      // [0,64) i row for M
    const int mjq = t & 3;       // j quad for M
    const int ujj = t >> 4;      // [0,16) j row for U
    const int ukq = t & 15;      // k float4 index for U

    for (int jt = 0; jt < 8; jt++) {
        const int jb = jt * KT;
        {
            const float2* mp = &Mb[(size_t)(it + mi) * 128 + jb + mjq * 4];
            const float4 mf0 = *(const float4*)mp;
            const float4 mf1 = *(const float4*)(mp + 2);
            Ms[mjq * 4 + 0][mi] = make_float2(mf0.x, mf0.y);
            Ms[mjq * 4 + 1][mi] = make_float2(mf0.z, mf0.w);
            Ms[mjq * 4 + 2][mi] = make_float2(mf1.x, mf1.y);
            Ms[mjq * 4 + 3][mi] = make_float2(mf1.z, mf1.w);
            const size_t off = GADDR(jb + ujj, kb0 + ukq * 4);
            const float4 uR = *(const float4*)(srcR + off);
            const float4 uI = *(const float4*)(srcI + off);
            Us[ujj][ukq * 4 + 0] = make_float2(uR.x, uI.x);
            Us[ujj][ukq * 4 + 1] = make_float2(uR.y, uI.y);
            Us[ujj][ukq * 4 + 2] = make_float2(uR.z, uI.z);
            Us[ujj][ukq * 4 + 3] = make_float2(uR.w, uI.w);
        }
        __syncthreads();

        #pragma unroll
        for (int jj = 0; jj < KT; jj++) {
            float4 m4[2], u4[2];
            #pragma unroll
            for (int q = 0; q < 2; q++) m4[q] = *(const float4*)&Ms[jj][2 * ti + 32 * q];
            #pragma unroll
            for (int q = 0; q < 2; q++) u4[q] = *(const float4*)&Us[jj][2 * tj + 32 * q];
            #pragma unroll
            for (int r = 0; r < 4; r++) {
                const float mx = (r & 1) ? m4[r >> 1].z : m4[r >> 1].x;
                const float my = (r & 1) ? m4[r >> 1].w : m4[r >> 1].y;
                #pragma unroll
                for (int c = 0; c < 4; c++) {
                    const float ux = (c & 1) ? u4[c >> 1].z : u4[c >> 1].x;
                    const float uy = (c & 1) ? u4[c >> 1].w : u4[c >> 1].y;
                    accr[r][c] = fmaf(mx,  ux, accr[r][c]);
                    accr[r][c] = fmaf(-my, uy, accr[r][c]);
                    acci[r][c] = fmaf(mx,  uy, acci[r][c]);
                    acci[r][c] = fmaf(my,  ux, acci[r][c]);
                }
            }
        }
        __syncthreads();
    }

    // epilogue: float2 stores along k
    #pragma unroll
    for (int r = 0; r < 4; r++) {
        const int i = it + 2 * ti + (r & 1) + 32 * (r >> 1);
        #pragma unroll
        for (int p = 0; p < 2; p++) {
            const int k = kb0 + 2 * tj + 32 * p;
            const size_t o2 = boff + (size_t)i * SI_ +
                (size_t)(k >> KL2_) * SKH_ + (size_t)(k & ((1 << KL2_) - 1));
            *(float2*)(dstR + o2) = make_float2(accr[r][2 * p], accr[r][2 * p + 1]);
            *(float2*)(dstI + o2) = make_float2(acci[r][2 * p], acci[r][2 * p + 1]);
        }
    }
    #undef GADDR
}

// =====================================================================
// mix64 (mode 2, d=64): u(b,j,k) = boff + j + (k&127)*64 + (k>>7)*8192;
// Proven R6-single-buffer fp32 version (unchanged this round).
// =====================================================================
__global__ __launch_bounds__(256)
void mix64_kernel(const float* __restrict__ srcR, const float* __restrict__ srcI,
                  const float2* __restrict__ M,
                  float* __restrict__ dstR, float* __restrict__ dstI)
{
    const int kb0 = blockIdx.x << 6;   // 64-wide k tile
    const int b   = blockIdx.y;

    const int t  = threadIdx.x;
    const int ti = t & 15;   // i groups
    const int tj = t >> 4;   // k groups

    __shared__ float2 Ms[KT][66];   // [jj][ii]
    __shared__ float2 Us[KT][66];   // [jj][kk]

    float accr[4][4] = {{0.f}}, acci[4][4] = {{0.f}};

    const size_t boff = (size_t)b * SSIZE;
    const float2* Mb  = M + (size_t)b * 64 * 64;
    const size_t koff = (size_t)(kb0 & 127) * 64 + (size_t)(kb0 >> 7) * 8192;

    // staging maps
    const int mi  = t >> 2;      // [0,64) i row for M
    const int mjq = t & 3;       // j quad for M
    const int ukk = t >> 2;      // [0,64) k for U
    const int ujq = t & 3;       // j quad for U

    for (int jt = 0; jt < 4; jt++) {
        const int jb = jt * KT;
        {
            const float2* mp = &Mb[(size_t)mi * 64 + jb + mjq * 4];
            const float4 mf0 = *(const float4*)mp;
            const float4 mf1 = *(const float4*)(mp + 2);
            Ms[mjq * 4 + 0][mi] = make_float2(mf0.x, mf0.y);
            Ms[mjq * 4 + 1][mi] = make_float2(mf0.z, mf0.w);
            Ms[mjq * 4 + 2][mi] = make_float2(mf1.x, mf1.y);
            Ms[mjq * 4 + 3][mi] = make_float2(mf1.z, mf1.w);
            const size_t off = boff + (size_t)(jb + ujq * 4) + koff + (size_t)ukk * 64;
            const float4 uR = *(const float4*)(srcR + off);
            const float4 uI = *(const float4*)(srcI + off);
            Us[ujq * 4 + 0][ukk] = make_float2(uR.x, uI.x);
            Us[ujq * 4 + 1][ukk] = make_float2(uR.y, uI.y);
            Us[ujq * 4 + 2][ukk] = make_float2(uR.z, uI.z);
            Us[ujq * 4 + 3][ukk] = make_float2(uR.w, uI.w);
        }
        __syncthreads();

        #pragma unroll
        for (int jj = 0; jj < KT; jj++) {
            float4 m4[2], u4[2];
            #pragma unroll
            for (int q = 0; q < 2; q++) m4[q] = *(const float4*)&Ms[jj][2 * ti + 32 * q];
            #pragma unroll
            for (int q = 0; q < 2; q++) u4[q] = *(const float4*)&Us[jj][2 * tj + 32 * q];
            #pragma unroll
            for (int r = 0; r < 4; r++) {
                const float mx = (r & 1) ? m4[r >> 1].z : m4[r >> 1].x;
                const float my = (r & 1) ? m4[r >> 1].w : m4[r >> 1].y;
                #pragma unroll
                for (int c = 0; c < 4; c++) {
                    const float ux = (c & 1) ? u4[c >> 1].z : u4[c >> 1].x;
                    const float uy = (c & 1) ? u4[c >> 1].w : u4[c >> 1].y;
                    accr[r][c] = fmaf(mx,  ux, accr[r][c]);
                    accr[r][c] = fmaf(-my, uy, accr[r][c]);
                    acci[r][c] = fmaf(mx,  uy, acci[r][c]);
                    acci[r][c] = fmaf(my,  ux, acci[r][c]);
                }
            }
        }
        __syncthreads();
    }

    // epilogue: float2 stores along i (i contiguous in dst)
    #pragma unroll
    for (int c = 0; c < 4; c++) {
        const int k = kb0 + 2 * tj + (c & 1) + 32 * (c >> 1);
        const size_t kbase = boff + (size_t)(k & 127) * 64 + (size_t)(k >> 7) * 8192;
        #pragma unroll
        for (int p = 0; p < 2; p++) {
            const int i = 2 * ti + 32 * p;
            *(float2*)(dstR + kbase + i) = make_float2(accr[2 * p][c], accr[2 * p + 1][c]);
            *(float2*)(dstI + kbase + i) = make_float2(acci[2 * p][c], acci[2 * p + 1][c]);
        }
    }
}

extern "C" void kernel_launch(void* const* d_in, const int* in_sizes, int n_in,
                              void* d_out, int out_size, void* d_ws, size_t ws_size,
                              hipStream_t stream)
{
    const float* xr  = (const float*)d_in[0];
    const float* xi  = (const float*)d_in[1];
    const float* w0r = (const float*)d_in[2];
    const float* w0i = (const float*)d_in[3];
    const float* w1r = (const float*)d_in[4];
    const float* w1i = (const float*)d_in[5];
    const float* w2r = (const float*)d_in[6];
    const float* w2i = (const float*)d_in[7];
    const float* lt  = (const float*)d_in[8];

    float* outR = (float*)d_out;
    float* outI = outR + (size_t)BATCH * SSIZE;

    float*  wsR = (float*)d_ws;
    float*  wsI = wsR + (size_t)BATCH * SSIZE;
    float*  Gf  = wsI + (size_t)BATCH * SSIZE;
    float2* Mf  = (float2*)(Gf + (size_t)BATCH * 128 * 128 * 2);

    const int nG = BATCH * 128 * 128 * 2;

    // ---------------- mode 0: d=128, SI=8192, KL2=13
    zero_kernel<<<dim3((nG + 255) / 256), 256, 0, stream>>>(Gf, nG);
    gram_mfma_kernel<8192, 13, 0><<<dim3(3, 32, BATCH), 256, 0, stream>>>(xr, xi, Gf, 256);
    score_kernel<<<dim3(128, BATCH), 128, 0, stream>>>(Gf, w0r, w0i, lt, Mf, 128);
    mix128_kernel<8192, 13, 0><<<dim3(128, 2, BATCH), 256, 0, stream>>>(xr, xi, Mf, outR, outI);

    // ---------------- mode 1: d=128, SI=64, KL2=6, SKH=8192
    zero_kernel<<<dim3((nG + 255) / 256), 256, 0, stream>>>(Gf, nG);
    gram_mfma_kernel<64, 6, 8192><<<dim3(3, 32, BATCH), 256, 0, stream>>>(outR, outI, Gf, 256);
    score_kernel<<<dim3(128, BATCH), 128, 0, stream>>>(Gf, w1r, w1i, lt, Mf, 128);
    mix128_kernel<64, 6, 8192><<<dim3(128, 2, BATCH), 256, 0, stream>>>(outR, outI, Mf, wsR, wsI);

    // ---------------- mode 2: d=64, SI=1, k: (k&127)*64 + (k>>7)*8192
    zero_kernel<<<dim3((nG + 255) / 256), 256, 0, stream>>>(Gf, nG);
    gram64_mfma_kernel<<<dim3(64, BATCH), 256, 0, stream>>>(wsR, wsI, Gf, 256);
    score_kernel<<<dim3(64, BATCH), 64, 0, stream>>>(Gf, w2r, w2i, lt, Mf, 64);
    mix64_kernel<<<dim3(256, BATCH), 256, 0, stream>>>(wsR, wsI, Mf, outR, outI);
}

// Round 3
// 603.589 us; speedup vs baseline: 1.5463x; 1.5463x over previous
//
#include <hip/hip_runtime.h>
#include <math.h>

#define BATCH 8
#define SSIZE 1048576   // 128*128*64
#define KT 16

// R9: gram atomics ELIMINATED (R2 counters: WRITE_SIZE 114.7MB vs 1MB useful,
// all pipes <17% => 8.4M contended atomicAdds dominated at ~39/ns).
// k-split blocks now store partial tiles to private slabs (plain stores,
// exclusive ownership), tiny reduce kernel sums them. Partials live in DEAD
// buffer phases (outR before it's written / wsR before mix writes it) =>
// zero extra workspace. zero_kernel launches removed.
// mix/score unchanged (proven R5/R6); gram MFMA math unchanged (proven R2,
// absmax 3e-5).

typedef short sh8 __attribute__((ext_vector_type(8)));
typedef float f32x4 __attribute__((ext_vector_type(4)));

#define MFMA16(a, b, c) __builtin_amdgcn_mfma_f32_16x16x32_bf16((a), (b), (c), 0, 0, 0)

__device__ __forceinline__ unsigned short bf_rne(float x) {
    unsigned u = __float_as_uint(x);
    unsigned r = u + 0x7fffu + ((u >> 16) & 1u);
    return (unsigned short)(r >> 16);
}

// split x into hi + lo bf16 (both RNE)
__device__ __forceinline__ void split1(float x, unsigned short &h, unsigned short &l) {
    h = bf_rne(x);
    float hf = __uint_as_float((unsigned)h << 16);
    l = bf_rne(x - hf);
}

__device__ __forceinline__ float f4c(const float4 &v, int c) {
    return c == 0 ? v.x : c == 1 ? v.y : c == 2 ? v.z : v.w;
}

// fragment load from a bf16 plane [rows][32 k] with XOR swizzle ((row&3)<<3 ushorts)
__device__ __forceinline__ sh8 ldfrag(const unsigned short *pl, int row, int kg) {
    const int idx = (row * 32 + kg * 8) ^ ((row & 3) << 3);
    return *(const sh8 *)(pl + idx);
}

// ---------------- partial-slab reduce: out[b][r] = sum_s in[b][s][r] --------
template<int NS, int PERB>   // PERB in float4 units
__global__ __launch_bounds__(256)
void reduce_kernel(const float4* __restrict__ in, float4* __restrict__ out) {
    const int gid = blockIdx.x * blockDim.x + threadIdx.x;
    const int b = gid / PERB, r = gid - b * PERB;
    const float4* p = in + (size_t)b * NS * PERB + r;
    float4 a = p[0];
    #pragma unroll
    for (int s = 1; s < NS; s++) {
        const float4 v = p[(size_t)s * PERB];
        a.x += v.x; a.y += v.y; a.z += v.z; a.w += v.w;
    }
    out[gid] = a;
}

// =====================================================================
// gram_mfma (modes 0/1, d=128): G = u u^T (no conj), symmetric.
// 3 tiles of 64x64: 0=(0,0), 1=(0,64)+mirror, 2=(64,64).
// Per k-step(32): stage 64 rows x 32 k per side as 4 bf16 planes
// (rH,rL,iH,iL), swizzled; 4 waves each own a 32x32 quadrant =
// 2x2 subtile-pairs x 12 mfma_16x16x32 (split-precision complex).
// Output: plain stores into private partial slab Gp[b][split][128][128][2].
// Three tile-blocks of one (b,split) write disjoint quadrants (tile1 also
// stores the mirror), covering the full 128x128 => no init, no atomics.
// =====================================================================
template<int SI_, int KL2_, int SKH_>
__global__ __launch_bounds__(256, 3)
void gram_mfma_kernel(const float* __restrict__ srcR, const float* __restrict__ srcI,
                      float* __restrict__ Gp, int kPerBlock)
{
    const int tile = blockIdx.x;             // 0,1,2
    const int it = (tile == 2) ? 64 : 0;
    const int jt = (tile == 0) ? 0 : 64;
    const bool diag = (it == jt);
    const int b  = blockIdx.z;
    const int k0 = blockIdx.y * kPerBlock;

    const int t    = threadIdx.x;
    const int lane = t & 63;
    const int wave = t >> 6;          // 0..3
    const int wr = wave & 1, wc = wave >> 1;

    __shared__ unsigned short SA[4][2048];   // planes rH,rL,iH,iL  [64 rows][32 k]
    __shared__ unsigned short SB[4][2048];

    const sh8 SGN = {(short)0x8000, (short)0x8000, (short)0x8000, (short)0x8000,
                     (short)0x8000, (short)0x8000, (short)0x8000, (short)0x8000};

    f32x4 gr[2][2], gi[2][2];
    const f32x4 z4 = {0.f, 0.f, 0.f, 0.f};
    #pragma unroll
    for (int x = 0; x < 2; x++)
        #pragma unroll
        for (int y = 0; y < 2; y++) { gr[x][y] = z4; gi[x][y] = z4; }

    const size_t boff = (size_t)b * SSIZE;
    const int nT = kPerBlock >> 5;

    // staging map: 8 k-quads x 32 row2 (rows row2, row2+32)
    const int kq   = t & 7;
    const int row2 = t >> 3;

    const int frow = lane & 15;
    const int kg   = lane >> 4;

    #define GADDR(ii, k) (boff + (size_t)(ii) * SI_ + \
        (size_t)((k) >> KL2_) * SKH_ + (size_t)((k) & ((1 << KL2_) - 1)))

    for (int kt = 0; kt < nT; kt++) {
        const int kb = k0 + kt * 32;
        #pragma unroll
        for (int m = 0; m < 2; m++) {
            const int row = row2 + 32 * m;
            const int idx = (row * 32 + kq * 4) ^ ((row & 3) << 3);
            {
                const size_t off = GADDR(it + row, kb + kq * 4);
                const float4 R = *(const float4*)(srcR + off);
                const float4 I = *(const float4*)(srcI + off);
                ushort4 rh, rl, ih, il;
                split1(R.x, rh.x, rl.x); split1(R.y, rh.y, rl.y);
                split1(R.z, rh.z, rl.z); split1(R.w, rh.w, rl.w);
                split1(I.x, ih.x, il.x); split1(I.y, ih.y, il.y);
                split1(I.z, ih.z, il.z); split1(I.w, ih.w, il.w);
                *(ushort4*)&SA[0][idx] = rh;
                *(ushort4*)&SA[1][idx] = rl;
                *(ushort4*)&SA[2][idx] = ih;
                *(ushort4*)&SA[3][idx] = il;
            }
            if (!diag) {
                const size_t off = GADDR(jt + row, kb + kq * 4);
                const float4 R = *(const float4*)(srcR + off);
                const float4 I = *(const float4*)(srcI + off);
                ushort4 rh, rl, ih, il;
                split1(R.x, rh.x, rl.x); split1(R.y, rh.y, rl.y);
                split1(R.z, rh.z, rl.z); split1(R.w, rh.w, rl.w);
                split1(I.x, ih.x, il.x); split1(I.y, ih.y, il.y);
                split1(I.z, ih.z, il.z); split1(I.w, ih.w, il.w);
                *(ushort4*)&SB[0][idx] = rh;
                *(ushort4*)&SB[1][idx] = rl;
                *(ushort4*)&SB[2][idx] = ih;
                *(ushort4*)&SB[3][idx] = il;
            }
        }
        __syncthreads();

        unsigned short (*BP)[2048] = diag ? SA : SB;

        sh8 a[2][4], na[2][2], bfr[2][4];
        #pragma unroll
        for (int s = 0; s < 2; s++) {
            const int row = wr * 32 + s * 16 + frow;
            #pragma unroll
            for (int p = 0; p < 4; p++) a[s][p] = ldfrag(&SA[p][0], row, kg);
            na[s][0] = a[s][2] ^ SGN;
            na[s][1] = a[s][3] ^ SGN;
        }
        #pragma unroll
        for (int s = 0; s < 2; s++) {
            const int row = wc * 32 + s * 16 + frow;
            #pragma unroll
            for (int p = 0; p < 4; p++) bfr[s][p] = ldfrag(&BP[p][0], row, kg);
        }

        #pragma unroll
        for (int sr = 0; sr < 2; sr++) {
            #pragma unroll
            for (int sc = 0; sc < 2; sc++) {
                f32x4 r = gr[sr][sc], q = gi[sr][sc];
                // Gr = Ar Br^T - Ai Bi^T  (split: HH + HL + LH)
                r = MFMA16(a[sr][0],  bfr[sc][0], r);
                r = MFMA16(a[sr][0],  bfr[sc][1], r);
                r = MFMA16(a[sr][1],  bfr[sc][0], r);
                r = MFMA16(na[sr][0], bfr[sc][2], r);
                r = MFMA16(na[sr][0], bfr[sc][3], r);
                r = MFMA16(na[sr][1], bfr[sc][2], r);
                // Gi = Ar Bi^T + Ai Br^T
                q = MFMA16(a[sr][0],  bfr[sc][2], q);
                q = MFMA16(a[sr][0],  bfr[sc][3], q);
                q = MFMA16(a[sr][1],  bfr[sc][2], q);
                q = MFMA16(a[sr][2],  bfr[sc][0], q);
                q = MFMA16(a[sr][2],  bfr[sc][1], q);
                q = MFMA16(a[sr][3],  bfr[sc][0], q);
                gr[sr][sc] = r; gi[sr][sc] = q;
            }
        }
        __syncthreads();
    }
    #undef GADDR

    // plain stores to private (b, split) slab — no atomics, no init
    float* Gb = Gp + ((size_t)b * gridDim.y + blockIdx.y) * (128 * 128 * 2);
    const int rb   = (lane >> 4) * 4;
    const int jcol = lane & 15;
    #pragma unroll
    for (int sr = 0; sr < 2; sr++)
        #pragma unroll
        for (int sc = 0; sc < 2; sc++)
            #pragma unroll
            for (int r = 0; r < 4; r++) {
                const int i = it + wr * 32 + sr * 16 + rb + r;
                const int j = jt + wc * 32 + sc * 16 + jcol;
                const float vr = gr[sr][sc][r], vi = gi[sr][sc][r];
                *(float2*)&Gb[(i * 128 + j) * 2] = make_float2(vr, vi);
                if (!diag)   // mirror: G[j][i] = G[i][j]
                    *(float2*)&Gb[(j * 128 + i) * 2] = make_float2(vr, vi);
            }
}

// =====================================================================
// gram64_mfma (mode 2, d=64): u(b,i,k) = boff + i + (k&127)*64 + (k>>7)*8192.
// i is contiguous => transposed staging (gather 2 k per i, b32 writes).
// Full 64x64 output per block, 4 waves x 32x32 quadrants.
// Output: plain stores into private slab Gp[b][split][64][64][2].
// =====================================================================
__global__ __launch_bounds__(256, 3)
void gram64_mfma_kernel(const float* __restrict__ srcR, const float* __restrict__ srcI,
                        float* __restrict__ Gp, int kPerBlock)
{
    const int b  = blockIdx.y;
    const int k0 = blockIdx.x * kPerBlock;

    const int t    = threadIdx.x;
    const int lane = t & 63;
    const int wave = t >> 6;
    const int wr = wave & 1, wc = wave >> 1;

    __shared__ unsigned short SA[4][2048];   // planes [64 i][32 k]

    const sh8 SGN = {(short)0x8000, (short)0x8000, (short)0x8000, (short)0x8000,
                     (short)0x8000, (short)0x8000, (short)0x8000, (short)0x8000};

    f32x4 gr[2][2], gi[2][2];
    const f32x4 z4 = {0.f, 0.f, 0.f, 0.f};
    #pragma unroll
    for (int x = 0; x < 2; x++)
        #pragma unroll
        for (int y = 0; y < 2; y++) { gr[x][y] = z4; gi[x][y] = z4; }

    const size_t boff = (size_t)b * SSIZE;
    const int nT = kPerBlock >> 5;

    // staging map: kp-major, 64B-chunk coalesced loads
    const int kp = t & 15;        // k = 2kp, 2kp+1 within tile
    const int i0 = (t >> 4) * 4;  // i quad

    const int frow = lane & 15;
    const int kg   = lane >> 4;

    for (int kt = 0; kt < nT; kt++) {
        const int kb = k0 + kt * 32;
        const int ke = kb + 2 * kp;
        const int ko = ke + 1;
        const size_t offE = boff + (size_t)(ke & 127) * 64 + (size_t)(ke >> 7) * 8192 + i0;
        const size_t offO = boff + (size_t)(ko & 127) * 64 + (size_t)(ko >> 7) * 8192 + i0;
        const float4 R0 = *(const float4*)(srcR + offE);
        const float4 I0 = *(const float4*)(srcI + offE);
        const float4 R1 = *(const float4*)(srcR + offO);
        const float4 I1 = *(const float4*)(srcI + offO);
        const int kw = 2 * kp;
        #pragma unroll
        for (int c = 0; c < 4; c++) {
            const int i   = i0 + c;
            const int idx = (i * 32 + kw) ^ ((i & 3) << 3);
            unsigned short h0, l0, h1, l1;
            split1(f4c(R0, c), h0, l0);
            split1(f4c(R1, c), h1, l1);
            *(ushort2*)&SA[0][idx] = make_ushort2(h0, h1);
            *(ushort2*)&SA[1][idx] = make_ushort2(l0, l1);
            split1(f4c(I0, c), h0, l0);
            split1(f4c(I1, c), h1, l1);
            *(ushort2*)&SA[2][idx] = make_ushort2(h0, h1);
            *(ushort2*)&SA[3][idx] = make_ushort2(l0, l1);
        }
        __syncthreads();

        sh8 a[2][4], na[2][2], bfr[2][4];
        #pragma unroll
        for (int s = 0; s < 2; s++) {
            const int row = wr * 32 + s * 16 + frow;
            #pragma unroll
            for (int p = 0; p < 4; p++) a[s][p] = ldfrag(&SA[p][0], row, kg);
            na[s][0] = a[s][2] ^ SGN;
            na[s][1] = a[s][3] ^ SGN;
        }
        #pragma unroll
        for (int s = 0; s < 2; s++) {
            const int row = wc * 32 + s * 16 + frow;
            #pragma unroll
            for (int p = 0; p < 4; p++) bfr[s][p] = ldfrag(&SA[p][0], row, kg);
        }

        #pragma unroll
        for (int sr = 0; sr < 2; sr++) {
            #pragma unroll
            for (int sc = 0; sc < 2; sc++) {
                f32x4 r = gr[sr][sc], q = gi[sr][sc];
                r = MFMA16(a[sr][0],  bfr[sc][0], r);
                r = MFMA16(a[sr][0],  bfr[sc][1], r);
                r = MFMA16(a[sr][1],  bfr[sc][0], r);
                r = MFMA16(na[sr][0], bfr[sc][2], r);
                r = MFMA16(na[sr][0], bfr[sc][3], r);
                r = MFMA16(na[sr][1], bfr[sc][2], r);
                q = MFMA16(a[sr][0],  bfr[sc][2], q);
                q = MFMA16(a[sr][0],  bfr[sc][3], q);
                q = MFMA16(a[sr][1],  bfr[sc][2], q);
                q = MFMA16(a[sr][2],  bfr[sc][0], q);
                q = MFMA16(a[sr][2],  bfr[sc][1], q);
                q = MFMA16(a[sr][3],  bfr[sc][0], q);
                gr[sr][sc] = r; gi[sr][sc] = q;
            }
        }
        __syncthreads();
    }

    float* Gb = Gp + ((size_t)b * gridDim.x + blockIdx.x) * (64 * 64 * 2);
    const int rb   = (lane >> 4) * 4;
    const int jcol = lane & 15;
    #pragma unroll
    for (int sr = 0; sr < 2; sr++)
        #pragma unroll
        for (int sc = 0; sc < 2; sc++)
            #pragma unroll
            for (int r = 0; r < 4; r++) {
                const int i = wr * 32 + sr * 16 + rb + r;
                const int j = wc * 32 + sc * 16 + jcol;
                *(float2*)&Gb[(i * 64 + j) * 2] = make_float2(gr[sr][sc][r], gi[sr][sc][r]);
            }
}

// ---------------- score/softmax/phase -> routing matrix M ----------------
__global__ __launch_bounds__(128)
void score_kernel(const float* __restrict__ G,
                  const float* __restrict__ Wre, const float* __restrict__ Wim,
                  const float* __restrict__ log_tau,
                  float2* __restrict__ Mout, int d)
{
    const int b = blockIdx.y;
    const int i = blockIdx.x;
    const int j = threadIdx.x;

    const float2* Gb = (const float2*)G + (size_t)b * d * d;

    float sre = 0.f, sim = 0.f;
    for (int l = 0; l < d; l++) {
        float wr = Wre[i * d + l];
        float wi = Wim[i * d + l];
        float2 g = Gb[l * d + j];
        sre = fmaf(wr, g.x, sre);
        sre = fmaf(-wi, g.y, sre);
        sim = fmaf(wr, g.y, sim);
        sim = fmaf(wi, g.x, sim);
    }

    float mag = sqrtf(sre * sre + sim * sim);
    float tau = fmaxf(expf(log_tau[0]), 1e-8f);
    float scale = tau * sqrtf((float)SSIZE / (float)d);
    float mval = mag / scale;

    __shared__ float red[128];
    red[j] = mval;
    __syncthreads();
    for (int s = d >> 1; s > 0; s >>= 1) {
        if (j < s) red[j] = fmaxf(red[j], red[j + s]);
        __syncthreads();
    }
    float mx = red[0];
    __syncthreads();
    float e = expf(mval - mx);
    red[j] = e;
    __syncthreads();
    for (int s = d >> 1; s > 0; s >>= 1) {
        if (j < s) red[j] += red[j + s];
        __syncthreads();
    }
    float routing = e / red[0];

    float safe = fmaxf(mag, 1e-8f);
    float pre, pim;
    if (mag > 1e-8f) { pre = sre / safe; pim = sim / safe; }
    else             { pre = 1.f;       pim = 0.f; }

    Mout[(size_t)b * d * d + i * d + j] = make_float2(routing * pre, routing * pim);
}

// =====================================================================
// mix128 (modes 0/1, d=128): dst(b,i,k) = sum_j M[b,i,j]*u(b,j,k).
// Proven R6-single-buffer fp32 version (unchanged this round).
// =====================================================================
template<int SI_, int KL2_, int SKH_>
__global__ __launch_bounds__(256)
void mix128_kernel(const float* __restrict__ srcR, const float* __restrict__ srcI,
                   const float2* __restrict__ M,
                   float* __restrict__ dstR, float* __restrict__ dstI)
{
    const int kb0 = blockIdx.x << 6;   // 64-wide k tile (aligned to KLO)
    const int it  = blockIdx.y << 6;   // 64-wide i tile
    const int b   = blockIdx.z;

    const int t  = threadIdx.x;
    const int ti = t & 15;   // i groups
    const int tj = t >> 4;   // k groups

    __shared__ float2 Ms[KT][66];   // [jj][ii]
    __shared__ float2 Us[KT][66];   // [jj][kk]

    float accr[4][4] = {{0.f}}, acci[4][4] = {{0.f}};

    const size_t boff = (size_t)b * SSIZE;
    const float2* Mb  = M + (size_t)b * 128 * 128;

    #define GADDR(jj, k) (boff + (size_t)(jj) * SI_ + \
        (size_t)((k) >> KL2_) * SKH_ + (size_t)((k) & ((1 << KL2_) - 1)))

    // staging maps
    const int mi  = t >> 2;      // [0,64) i row for M
    const int mjq = t & 3;       // j quad for M
    const int ujj = t >> 4;      // [0,16) j row for U
    const int ukq = t & 15;      // k float4 index for U

    for (int jt = 0; jt < 8; jt++) {
        const int jb = jt * KT;
        {
            const float2* mp = &Mb[(size_t)(it + mi) * 128 + jb + mjq * 4];
            const float4 mf0 = *(const float4*)mp;
            const float4 mf1 = *(const float4*)(mp + 2);
            Ms[mjq * 4 + 0][mi] = make_float2(mf0.x, mf0.y);
            Ms[mjq * 4 + 1][mi] = make_float2(mf0.z, mf0.w);
            Ms[mjq * 4 + 2][mi] = make_float2(mf1.x, mf1.y);
            Ms[mjq * 4 + 3][mi] = make_float2(mf1.z, mf1.w);
            const size_t off = GADDR(jb + ujj, kb0 + ukq * 4);
            const float4 uR = *(const float4*)(srcR + off);
            const float4 uI = *(const float4*)(srcI + off);
            Us[ujj][ukq * 4 + 0] = make_float2(uR.x, uI.x);
            Us[ujj][ukq * 4 + 1] = make_float2(uR.y, uI.y);
            Us[ujj][ukq * 4 + 2] = make_float2(uR.z, uI.z);
            Us[ujj][ukq * 4 + 3] = make_float2(uR.w, uI.w);
        }
        __syncthreads();

        #pragma unroll
        for (int jj = 0; jj < KT; jj++) {
            float4 m4[2], u4[2];
            #pragma unroll
            for (int q = 0; q < 2; q++) m4[q] = *(const float4*)&Ms[jj][2 * ti + 32 * q];
            #pragma unroll
            for (int q = 0; q < 2; q++) u4[q] = *(const float4*)&Us[jj][2 * tj + 32 * q];
            #pragma unroll
            for (int r = 0; r < 4; r++) {
                const float mx = (r & 1) ? m4[r >> 1].z : m4[r >> 1].x;
                const float my = (r & 1) ? m4[r >> 1].w : m4[r >> 1].y;
                #pragma unroll
                for (int c = 0; c < 4; c++) {
                    const float ux = (c & 1) ? u4[c >> 1].z : u4[c >> 1].x;
                    const float uy = (c & 1) ? u4[c >> 1].w : u4[c >> 1].y;
                    accr[r][c] = fmaf(mx,  ux, accr[r][c]);
                    accr[r][c] = fmaf(-my, uy, accr[r][c]);
                    acci[r][c] = fmaf(mx,  uy, acci[r][c]);
                    acci[r][c] = fmaf(my,  ux, acci[r][c]);
                }
            }
        }
        __syncthreads();
    }

    // epilogue: float2 stores along k
    #pragma unroll
    for (int r = 0; r < 4; r++) {
        const int i = it + 2 * ti + (r & 1) + 32 * (r >> 1);
        #pragma unroll
        for (int p = 0; p < 2; p++) {
            const int k = kb0 + 2 * tj + 32 * p;
            const size_t o2 = boff + (size_t)i * SI_ +
                (size_t)(k >> KL2_) * SKH_ + (size_t)(k & ((1 << KL2_) - 1));
            *(float2*)(dstR + o2) = make_float2(accr[r][2 * p], accr[r][2 * p + 1]);
            *(float2*)(dstI + o2) = make_float2(acci[r][2 * p], acci[r][2 * p + 1]);
        }
    }
    #undef GADDR
}

// =====================================================================
// mix64 (mode 2, d=64): u(b,j,k) = boff + j + (k&127)*64 + (k>>7)*8192;
// Proven R6-single-buffer fp32 version (unchanged this round).
// =====================================================================
__global__ __launch_bounds__(256)
void mix64_kernel(const float* __restrict__ srcR, const float* __restrict__ srcI,
                  const float2* __restrict__ M,
                  float* __restrict__ dstR, float* __restrict__ dstI)
{
    const int kb0 = blockIdx.x << 6;   // 64-wide k tile
    const int b   = blockIdx.y;

    const int t  = threadIdx.x;
    const int ti = t & 15;   // i groups
    const int tj = t >> 4;   // k groups

    __shared__ float2 Ms[KT][66];   // [jj][ii]
    __shared__ float2 Us[KT][66];   // [jj][kk]

    float accr[4][4] = {{0.f}}, acci[4][4] = {{0.f}};

    const size_t boff = (size_t)b * SSIZE;
    const float2* Mb  = M + (size_t)b * 64 * 64;
    const size_t koff = (size_t)(kb0 & 127) * 64 + (size_t)(kb0 >> 7) * 8192;

    // staging maps
    const int mi  = t >> 2;      // [0,64) i row for M
    const int mjq = t & 3;       // j quad for M
    const int ukk = t >> 2;      // [0,64) k for U
    const int ujq = t & 3;       // j quad for U

    for (int jt = 0; jt < 4; jt++) {
        const int jb = jt * KT;
        {
            const float2* mp = &Mb[(size_t)mi * 64 + jb + mjq * 4];
            const float4 mf0 = *(const float4*)mp;
            const float4 mf1 = *(const float4*)(mp + 2);
            Ms[mjq * 4 + 0][mi] = make_float2(mf0.x, mf0.y);
            Ms[mjq * 4 + 1][mi] = make_float2(mf0.z, mf0.w);
            Ms[mjq * 4 + 2][mi] = make_float2(mf1.x, mf1.y);
            Ms[mjq * 4 + 3][mi] = make_float2(mf1.z, mf1.w);
            const size_t off = boff + (size_t)(jb + ujq * 4) + koff + (size_t)ukk * 64;
            const float4 uR = *(const float4*)(srcR + off);
            const float4 uI = *(const float4*)(srcI + off);
            Us[ujq * 4 + 0][ukk] = make_float2(uR.x, uI.x);
            Us[ujq * 4 + 1][ukk] = make_float2(uR.y, uI.y);
            Us[ujq * 4 + 2][ukk] = make_float2(uR.z, uI.z);
            Us[ujq * 4 + 3][ukk] = make_float2(uR.w, uI.w);
        }
        __syncthreads();

        #pragma unroll
        for (int jj = 0; jj < KT; jj++) {
            float4 m4[2], u4[2];
            #pragma unroll
            for (int q = 0; q < 2; q++) m4[q] = *(const float4*)&Ms[jj][2 * ti + 32 * q];
            #pragma unroll
            for (int q = 0; q < 2; q++) u4[q] = *(const float4*)&Us[jj][2 * tj + 32 * q];
            #pragma unroll
            for (int r = 0; r < 4; r++) {
                const float mx = (r & 1) ? m4[r >> 1].z : m4[r >> 1].x;
                const float my = (r & 1) ? m4[r >> 1].w : m4[r >> 1].y;
                #pragma unroll
                for (int c = 0; c < 4; c++) {
                    const float ux = (c & 1) ? u4[c >> 1].z : u4[c >> 1].x;
                    const float uy = (c & 1) ? u4[c >> 1].w : u4[c >> 1].y;
                    accr[r][c] = fmaf(mx,  ux, accr[r][c]);
                    accr[r][c] = fmaf(-my, uy, accr[r][c]);
                    acci[r][c] = fmaf(mx,  uy, acci[r][c]);
                    acci[r][c] = fmaf(my,  ux, acci[r][c]);
                }
            }
        }
        __syncthreads();
    }

    // epilogue: float2 stores along i (i contiguous in dst)
    #pragma unroll
    for (int c = 0; c < 4; c++) {
        const int k = kb0 + 2 * tj + (c & 1) + 32 * (c >> 1);
        const size_t kbase = boff + (size_t)(k & 127) * 64 + (size_t)(k >> 7) * 8192;
        #pragma unroll
        for (int p = 0; p < 2; p++) {
            const int i = 2 * ti + 32 * p;
            *(float2*)(dstR + kbase + i) = make_float2(accr[2 * p][c], accr[2 * p + 1][c]);
            *(float2*)(dstI + kbase + i) = make_float2(acci[2 * p][c], acci[2 * p + 1][c]);
        }
    }
}

extern "C" void kernel_launch(void* const* d_in, const int* in_sizes, int n_in,
                              void* d_out, int out_size, void* d_ws, size_t ws_size,
                              hipStream_t stream)
{
    const float* xr  = (const float*)d_in[0];
    const float* xi  = (const float*)d_in[1];
    const float* w0r = (const float*)d_in[2];
    const float* w0i = (const float*)d_in[3];
    const float* w1r = (const float*)d_in[4];
    const float* w1i = (const float*)d_in[5];
    const float* w2r = (const float*)d_in[6];
    const float* w2i = (const float*)d_in[7];
    const float* lt  = (const float*)d_in[8];

    float* outR = (float*)d_out;
    float* outI = outR + (size_t)BATCH * SSIZE;

    float*  wsR = (float*)d_ws;
    float*  wsI = wsR + (size_t)BATCH * SSIZE;
    float*  Gf  = wsI + (size_t)BATCH * SSIZE;
    float2* Mf  = (float2*)(Gf + (size_t)BATCH * 128 * 128 * 2);

    // Partial slabs live in DEAD buffer phases (no extra workspace):
    //  mode 0: outR  (written by mix128-mode0 only AFTER reduce consumed it)
    //  mode 1: wsR   (written by mix128-mode1 only AFTER reduce consumed it)
    //  mode 2: outR  (mode-0 output already consumed; mix64 overwrites later)
    // NS=16 (d=128): 8b*16*128*128*2*4B = 16.8MB < 32MB slab. grid 3*16*8=384.
    // NS=32 (d=64):  8b*32*64*64*2*4B   =  8.4MB < 32MB slab. grid 32*8=256.

    // ---------------- mode 0: d=128, SI=8192, KL2=13
    gram_mfma_kernel<8192, 13, 0><<<dim3(3, 16, BATCH), 256, 0, stream>>>(xr, xi, outR, 512);
    reduce_kernel<16, 8192><<<dim3(256), 256, 0, stream>>>((const float4*)outR, (float4*)Gf);
    score_kernel<<<dim3(128, BATCH), 128, 0, stream>>>(Gf, w0r, w0i, lt, Mf, 128);
    mix128_kernel<8192, 13, 0><<<dim3(128, 2, BATCH), 256, 0, stream>>>(xr, xi, Mf, outR, outI);

    // ---------------- mode 1: d=128, SI=64, KL2=6, SKH=8192
    gram_mfma_kernel<64, 6, 8192><<<dim3(3, 16, BATCH), 256, 0, stream>>>(outR, outI, wsR, 512);
    reduce_kernel<16, 8192><<<dim3(256), 256, 0, stream>>>((const float4*)wsR, (float4*)Gf);
    score_kernel<<<dim3(128, BATCH), 128, 0, stream>>>(Gf, w1r, w1i, lt, Mf, 128);
    mix128_kernel<64, 6, 8192><<<dim3(128, 2, BATCH), 256, 0, stream>>>(outR, outI, Mf, wsR, wsI);

    // ---------------- mode 2: d=64, SI=1, k: (k&127)*64 + (k>>7)*8192
    gram64_mfma_kernel<<<dim3(32, BATCH), 256, 0, stream>>>(wsR, wsI, outR, 512);
    reduce_kernel<32, 2048><<<dim3(64), 256, 0, stream>>>((const float4*)outR, (float4*)Gf);
    score_kernel<<<dim3(64, BATCH), 64, 0, stream>>>(Gf, w2r, w2i, lt, Mf, 64);
    mix64_kernel<<<dim3(256, BATCH), 256, 0, stream>>>(wsR, wsI, Mf, outR, outI);
}

// Round 4
// 446.888 us; speedup vs baseline: 2.0885x; 1.3506x over previous
//
#include <hip/hip_runtime.h>
#include <math.h>

#define BATCH 8
#define SSIZE 1048576   // 128*128*64

// R10: mix kernels converted to MFMA bf16 split-precision (R3 counters:
// mix128 fp32 was VALU-bound, MfmaUtil 0.0, VALUBusy 67%, 116us x2).
// Operand order per mode chosen so C/D reg layout gives float4 epilogue
// stores on the contiguous axis. LDS planes pitch-40 (bank-enumerated:
// fragment b128 reads at conflict floor, staging writes <=2-way).
// gram/reduce/score unchanged (proven R3: 603us, absmax 3.05e-5).

typedef short sh8 __attribute__((ext_vector_type(8)));
typedef float f32x4 __attribute__((ext_vector_type(4)));

#define MFMA16(a, b, c) __builtin_amdgcn_mfma_f32_16x16x32_bf16((a), (b), (c), 0, 0, 0)

__device__ __forceinline__ unsigned short bf_rne(float x) {
    unsigned u = __float_as_uint(x);
    unsigned r = u + 0x7fffu + ((u >> 16) & 1u);
    return (unsigned short)(r >> 16);
}

// split x into hi + lo bf16 (both RNE)
__device__ __forceinline__ void split1(float x, unsigned short &h, unsigned short &l) {
    h = bf_rne(x);
    float hf = __uint_as_float((unsigned)h << 16);
    l = bf_rne(x - hf);
}

// split two floats, pack hi pair / lo pair as u32 (a in low 16, b in high)
__device__ __forceinline__ void split2(float a, float b, unsigned &hh, unsigned &ll) {
    unsigned short ha = bf_rne(a), hb = bf_rne(b);
    hh = (unsigned)ha | ((unsigned)hb << 16);
    float ra = a - __uint_as_float((unsigned)ha << 16);
    float rb = b - __uint_as_float((unsigned)hb << 16);
    ll = (unsigned)bf_rne(ra) | ((unsigned)bf_rne(rb) << 16);
}

__device__ __forceinline__ float f4c(const float4 &v, int c) {
    return c == 0 ? v.x : c == 1 ? v.y : c == 2 ? v.z : v.w;
}

// fragment load, pitch-32 planes with XOR swizzle (gram kernels, proven)
__device__ __forceinline__ sh8 ldfrag(const unsigned short *pl, int row, int kg) {
    const int idx = (row * 32 + kg * 8) ^ ((row & 3) << 3);
    return *(const sh8 *)(pl + idx);
}

// fragment load, pitch-40 planes, no swizzle (mix kernels; bank-optimal)
__device__ __forceinline__ sh8 ldfrag40(const unsigned short *pl, int row, int kg) {
    return *(const sh8 *)(pl + row * 40 + kg * 8);
}

// ---------------- partial-slab reduce: out[b][r] = sum_s in[b][s][r] --------
template<int NS, int PERB>   // PERB in float4 units
__global__ __launch_bounds__(256)
void reduce_kernel(const float4* __restrict__ in, float4* __restrict__ out) {
    const int gid = blockIdx.x * blockDim.x + threadIdx.x;
    const int b = gid / PERB, r = gid - b * PERB;
    const float4* p = in + (size_t)b * NS * PERB + r;
    float4 a = p[0];
    #pragma unroll
    for (int s = 1; s < NS; s++) {
        const float4 v = p[(size_t)s * PERB];
        a.x += v.x; a.y += v.y; a.z += v.z; a.w += v.w;
    }
    out[gid] = a;
}

// =====================================================================
// gram_mfma (modes 0/1, d=128): G = u u^T, symmetric. Unchanged from R3.
// =====================================================================
template<int SI_, int KL2_, int SKH_>
__global__ __launch_bounds__(256, 3)
void gram_mfma_kernel(const float* __restrict__ srcR, const float* __restrict__ srcI,
                      float* __restrict__ Gp, int kPerBlock)
{
    const int tile = blockIdx.x;             // 0,1,2
    const int it = (tile == 2) ? 64 : 0;
    const int jt = (tile == 0) ? 0 : 64;
    const bool diag = (it == jt);
    const int b  = blockIdx.z;
    const int k0 = blockIdx.y * kPerBlock;

    const int t    = threadIdx.x;
    const int lane = t & 63;
    const int wave = t >> 6;          // 0..3
    const int wr = wave & 1, wc = wave >> 1;

    __shared__ unsigned short SA[4][2048];   // planes rH,rL,iH,iL  [64 rows][32 k]
    __shared__ unsigned short SB[4][2048];

    const sh8 SGN = {(short)0x8000, (short)0x8000, (short)0x8000, (short)0x8000,
                     (short)0x8000, (short)0x8000, (short)0x8000, (short)0x8000};

    f32x4 gr[2][2], gi[2][2];
    const f32x4 z4 = {0.f, 0.f, 0.f, 0.f};
    #pragma unroll
    for (int x = 0; x < 2; x++)
        #pragma unroll
        for (int y = 0; y < 2; y++) { gr[x][y] = z4; gi[x][y] = z4; }

    const size_t boff = (size_t)b * SSIZE;
    const int nT = kPerBlock >> 5;

    const int kq   = t & 7;
    const int row2 = t >> 3;

    const int frow = lane & 15;
    const int kg   = lane >> 4;

    #define GADDR(ii, k) (boff + (size_t)(ii) * SI_ + \
        (size_t)((k) >> KL2_) * SKH_ + (size_t)((k) & ((1 << KL2_) - 1)))

    for (int kt = 0; kt < nT; kt++) {
        const int kb = k0 + kt * 32;
        #pragma unroll
        for (int m = 0; m < 2; m++) {
            const int row = row2 + 32 * m;
            const int idx = (row * 32 + kq * 4) ^ ((row & 3) << 3);
            {
                const size_t off = GADDR(it + row, kb + kq * 4);
                const float4 R = *(const float4*)(srcR + off);
                const float4 I = *(const float4*)(srcI + off);
                ushort4 rh, rl, ih, il;
                split1(R.x, rh.x, rl.x); split1(R.y, rh.y, rl.y);
                split1(R.z, rh.z, rl.z); split1(R.w, rh.w, rl.w);
                split1(I.x, ih.x, il.x); split1(I.y, ih.y, il.y);
                split1(I.z, ih.z, il.z); split1(I.w, ih.w, il.w);
                *(ushort4*)&SA[0][idx] = rh;
                *(ushort4*)&SA[1][idx] = rl;
                *(ushort4*)&SA[2][idx] = ih;
                *(ushort4*)&SA[3][idx] = il;
            }
            if (!diag) {
                const size_t off = GADDR(jt + row, kb + kq * 4);
                const float4 R = *(const float4*)(srcR + off);
                const float4 I = *(const float4*)(srcI + off);
                ushort4 rh, rl, ih, il;
                split1(R.x, rh.x, rl.x); split1(R.y, rh.y, rl.y);
                split1(R.z, rh.z, rl.z); split1(R.w, rh.w, rl.w);
                split1(I.x, ih.x, il.x); split1(I.y, ih.y, il.y);
                split1(I.z, ih.z, il.z); split1(I.w, ih.w, il.w);
                *(ushort4*)&SB[0][idx] = rh;
                *(ushort4*)&SB[1][idx] = rl;
                *(ushort4*)&SB[2][idx] = ih;
                *(ushort4*)&SB[3][idx] = il;
            }
        }
        __syncthreads();

        unsigned short (*BP)[2048] = diag ? SA : SB;

        sh8 a[2][4], na[2][2], bfr[2][4];
        #pragma unroll
        for (int s = 0; s < 2; s++) {
            const int row = wr * 32 + s * 16 + frow;
            #pragma unroll
            for (int p = 0; p < 4; p++) a[s][p] = ldfrag(&SA[p][0], row, kg);
            na[s][0] = a[s][2] ^ SGN;
            na[s][1] = a[s][3] ^ SGN;
        }
        #pragma unroll
        for (int s = 0; s < 2; s++) {
            const int row = wc * 32 + s * 16 + frow;
            #pragma unroll
            for (int p = 0; p < 4; p++) bfr[s][p] = ldfrag(&BP[p][0], row, kg);
        }

        #pragma unroll
        for (int sr = 0; sr < 2; sr++) {
            #pragma unroll
            for (int sc = 0; sc < 2; sc++) {
                f32x4 r = gr[sr][sc], q = gi[sr][sc];
                r = MFMA16(a[sr][0],  bfr[sc][0], r);
                r = MFMA16(a[sr][0],  bfr[sc][1], r);
                r = MFMA16(a[sr][1],  bfr[sc][0], r);
                r = MFMA16(na[sr][0], bfr[sc][2], r);
                r = MFMA16(na[sr][0], bfr[sc][3], r);
                r = MFMA16(na[sr][1], bfr[sc][2], r);
                q = MFMA16(a[sr][0],  bfr[sc][2], q);
                q = MFMA16(a[sr][0],  bfr[sc][3], q);
                q = MFMA16(a[sr][1],  bfr[sc][2], q);
                q = MFMA16(a[sr][2],  bfr[sc][0], q);
                q = MFMA16(a[sr][2],  bfr[sc][1], q);
                q = MFMA16(a[sr][3],  bfr[sc][0], q);
                gr[sr][sc] = r; gi[sr][sc] = q;
            }
        }
        __syncthreads();
    }
    #undef GADDR

    float* Gb = Gp + ((size_t)b * gridDim.y + blockIdx.y) * (128 * 128 * 2);
    const int rb   = (lane >> 4) * 4;
    const int jcol = lane & 15;
    #pragma unroll
    for (int sr = 0; sr < 2; sr++)
        #pragma unroll
        for (int sc = 0; sc < 2; sc++)
            #pragma unroll
            for (int r = 0; r < 4; r++) {
                const int i = it + wr * 32 + sr * 16 + rb + r;
                const int j = jt + wc * 32 + sc * 16 + jcol;
                const float vr = gr[sr][sc][r], vi = gi[sr][sc][r];
                *(float2*)&Gb[(i * 128 + j) * 2] = make_float2(vr, vi);
                if (!diag)
                    *(float2*)&Gb[(j * 128 + i) * 2] = make_float2(vr, vi);
            }
}

// =====================================================================
// gram64_mfma (mode 2, d=64). Unchanged from R3.
// =====================================================================
__global__ __launch_bounds__(256, 3)
void gram64_mfma_kernel(const float* __restrict__ srcR, const float* __restrict__ srcI,
                        float* __restrict__ Gp, int kPerBlock)
{
    const int b  = blockIdx.y;
    const int k0 = blockIdx.x * kPerBlock;

    const int t    = threadIdx.x;
    const int lane = t & 63;
    const int wave = t >> 6;
    const int wr = wave & 1, wc = wave >> 1;

    __shared__ unsigned short SA[4][2048];   // planes [64 i][32 k]

    const sh8 SGN = {(short)0x8000, (short)0x8000, (short)0x8000, (short)0x8000,
                     (short)0x8000, (short)0x8000, (short)0x8000, (short)0x8000};

    f32x4 gr[2][2], gi[2][2];
    const f32x4 z4 = {0.f, 0.f, 0.f, 0.f};
    #pragma unroll
    for (int x = 0; x < 2; x++)
        #pragma unroll
        for (int y = 0; y < 2; y++) { gr[x][y] = z4; gi[x][y] = z4; }

    const size_t boff = (size_t)b * SSIZE;
    const int nT = kPerBlock >> 5;

    const int kp = t & 15;        // k = 2kp, 2kp+1 within tile
    const int i0 = (t >> 4) * 4;  // i quad

    const int frow = lane & 15;
    const int kg   = lane >> 4;

    for (int kt = 0; kt < nT; kt++) {
        const int kb = k0 + kt * 32;
        const int ke = kb + 2 * kp;
        const int ko = ke + 1;
        const size_t offE = boff + (size_t)(ke & 127) * 64 + (size_t)(ke >> 7) * 8192 + i0;
        const size_t offO = boff + (size_t)(ko & 127) * 64 + (size_t)(ko >> 7) * 8192 + i0;
        const float4 R0 = *(const float4*)(srcR + offE);
        const float4 I0 = *(const float4*)(srcI + offE);
        const float4 R1 = *(const float4*)(srcR + offO);
        const float4 I1 = *(const float4*)(srcI + offO);
        const int kw = 2 * kp;
        #pragma unroll
        for (int c = 0; c < 4; c++) {
            const int i   = i0 + c;
            const int idx = (i * 32 + kw) ^ ((i & 3) << 3);
            unsigned short h0, l0, h1, l1;
            split1(f4c(R0, c), h0, l0);
            split1(f4c(R1, c), h1, l1);
            *(ushort2*)&SA[0][idx] = make_ushort2(h0, h1);
            *(ushort2*)&SA[1][idx] = make_ushort2(l0, l1);
            split1(f4c(I0, c), h0, l0);
            split1(f4c(I1, c), h1, l1);
            *(ushort2*)&SA[2][idx] = make_ushort2(h0, h1);
            *(ushort2*)&SA[3][idx] = make_ushort2(l0, l1);
        }
        __syncthreads();

        sh8 a[2][4], na[2][2], bfr[2][4];
        #pragma unroll
        for (int s = 0; s < 2; s++) {
            const int row = wr * 32 + s * 16 + frow;
            #pragma unroll
            for (int p = 0; p < 4; p++) a[s][p] = ldfrag(&SA[p][0], row, kg);
            na[s][0] = a[s][2] ^ SGN;
            na[s][1] = a[s][3] ^ SGN;
        }
        #pragma unroll
        for (int s = 0; s < 2; s++) {
            const int row = wc * 32 + s * 16 + frow;
            #pragma unroll
            for (int p = 0; p < 4; p++) bfr[s][p] = ldfrag(&SA[p][0], row, kg);
        }

        #pragma unroll
        for (int sr = 0; sr < 2; sr++) {
            #pragma unroll
            for (int sc = 0; sc < 2; sc++) {
                f32x4 r = gr[sr][sc], q = gi[sr][sc];
                r = MFMA16(a[sr][0],  bfr[sc][0], r);
                r = MFMA16(a[sr][0],  bfr[sc][1], r);
                r = MFMA16(a[sr][1],  bfr[sc][0], r);
                r = MFMA16(na[sr][0], bfr[sc][2], r);
                r = MFMA16(na[sr][0], bfr[sc][3], r);
                r = MFMA16(na[sr][1], bfr[sc][2], r);
                q = MFMA16(a[sr][0],  bfr[sc][2], q);
                q = MFMA16(a[sr][0],  bfr[sc][3], q);
                q = MFMA16(a[sr][1],  bfr[sc][2], q);
                q = MFMA16(a[sr][2],  bfr[sc][0], q);
                q = MFMA16(a[sr][2],  bfr[sc][1], q);
                q = MFMA16(a[sr][3],  bfr[sc][0], q);
                gr[sr][sc] = r; gi[sr][sc] = q;
            }
        }
        __syncthreads();
    }

    float* Gb = Gp + ((size_t)b * gridDim.x + blockIdx.x) * (64 * 64 * 2);
    const int rb   = (lane >> 4) * 4;
    const int jcol = lane & 15;
    #pragma unroll
    for (int sr = 0; sr < 2; sr++)
        #pragma unroll
        for (int sc = 0; sc < 2; sc++)
            #pragma unroll
            for (int r = 0; r < 4; r++) {
                const int i = wr * 32 + sr * 16 + rb + r;
                const int j = wc * 32 + sc * 16 + jcol;
                *(float2*)&Gb[(i * 64 + j) * 2] = make_float2(gr[sr][sc][r], gi[sr][sc][r]);
            }
}

// ---------------- score/softmax/phase -> routing matrix M ----------------
__global__ __launch_bounds__(128)
void score_kernel(const float* __restrict__ G,
                  const float* __restrict__ Wre, const float* __restrict__ Wim,
                  const float* __restrict__ log_tau,
                  float2* __restrict__ Mout, int d)
{
    const int b = blockIdx.y;
    const int i = blockIdx.x;
    const int j = threadIdx.x;

    const float2* Gb = (const float2*)G + (size_t)b * d * d;

    float sre = 0.f, sim = 0.f;
    for (int l = 0; l < d; l++) {
        float wr = Wre[i * d + l];
        float wi = Wim[i * d + l];
        float2 g = Gb[l * d + j];
        sre = fmaf(wr, g.x, sre);
        sre = fmaf(-wi, g.y, sre);
        sim = fmaf(wr, g.y, sim);
        sim = fmaf(wi, g.x, sim);
    }

    float mag = sqrtf(sre * sre + sim * sim);
    float tau = fmaxf(expf(log_tau[0]), 1e-8f);
    float scale = tau * sqrtf((float)SSIZE / (float)d);
    float mval = mag / scale;

    __shared__ float red[128];
    red[j] = mval;
    __syncthreads();
    for (int s = d >> 1; s > 0; s >>= 1) {
        if (j < s) red[j] = fmaxf(red[j], red[j + s]);
        __syncthreads();
    }
    float mx = red[0];
    __syncthreads();
    float e = expf(mval - mx);
    red[j] = e;
    __syncthreads();
    for (int s = d >> 1; s > 0; s >>= 1) {
        if (j < s) red[j] += red[j + s];
        __syncthreads();
    }
    float routing = e / red[0];

    float safe = fmaxf(mag, 1e-8f);
    float pre, pim;
    if (mag > 1e-8f) { pre = sre / safe; pim = sim / safe; }
    else             { pre = 1.f;       pim = 0.f; }

    Mout[(size_t)b * d * d + i * d + j] = make_float2(routing * pre, routing * pim);
}

// =====================================================================
// mix128_mfma (modes 0/1, d=128): dst(b,i,k) = sum_j M[b,i,j]*u(b,j,k).
// A = u^T (rows=kcol, red=j), B = M (rows=i) => D rows = kcol: each lane
// holds 4 consecutive k => float4 epilogue on contiguous k axis.
// LDS: pitch-40 planes (bank-optimal for b128 frag reads, no swizzle).
// =====================================================================
template<int SI_, int KL2_, int SKH_>
__global__ __launch_bounds__(256, 3)
void mix128_mfma_kernel(const float* __restrict__ srcR, const float* __restrict__ srcI,
                        const float2* __restrict__ M,
                        float* __restrict__ dstR, float* __restrict__ dstI)
{
    const int kb0 = blockIdx.x << 6;   // 64-wide k tile
    const int it  = blockIdx.y << 6;   // 64-wide i tile
    const int b   = blockIdx.z;

    const int t    = threadIdx.x;
    const int lane = t & 63;
    const int wave = t >> 6;
    const int wr = wave & 1, wc = wave >> 1;   // wr: k half, wc: i half

    __shared__ unsigned short UP[4][2560];   // u^T planes [kcol 0..63][j 0..31], pitch 40
    __shared__ unsigned short MP[4][2560];   // M   planes [i    0..63][j 0..31], pitch 40

    const sh8 SGN = {(short)0x8000, (short)0x8000, (short)0x8000, (short)0x8000,
                     (short)0x8000, (short)0x8000, (short)0x8000, (short)0x8000};

    f32x4 gr[2][2], gi[2][2];     // [sr: k-sub][sc: i-sub]
    const f32x4 z4 = {0.f, 0.f, 0.f, 0.f};
    #pragma unroll
    for (int x = 0; x < 2; x++)
        #pragma unroll
        for (int y = 0; y < 2; y++) { gr[x][y] = z4; gi[x][y] = z4; }

    const size_t boff = (size_t)b * SSIZE;
    const float2* Mb  = M + (size_t)b * 128 * 128;

    #define GADDR(jj, k) (boff + (size_t)(jj) * SI_ + \
        (size_t)((k) >> KL2_) * SKH_ + (size_t)((k) & ((1 << KL2_) - 1)))

    // staging maps
    const int ujp = t & 15;        // j pair: j0 = 2*ujp  (LDS-write bank-free map)
    const int uq  = t >> 4;        // k quad: kc0 = 4*uq
    const int mi  = t >> 2;        // i row for M
    const int mj8 = (t & 3) * 8;   // j octet for M

    const int frow = lane & 15;
    const int kg   = lane >> 4;

    for (int jt = 0; jt < 4; jt++) {
        const int jb = jt * 32;
        // ---- stage M: 64 i x 32 j, 4 planes, uint4 stores (bank-floor)
        {
            const float2* mp = &Mb[(size_t)(it + mi) * 128 + jb + mj8];
            const float4 m0 = *(const float4*)(mp);
            const float4 m1 = *(const float4*)(mp + 2);
            const float4 m2 = *(const float4*)(mp + 4);
            const float4 m3 = *(const float4*)(mp + 6);
            unsigned rh0, rl0, ih0, il0, rh1, rl1, ih1, il1;
            unsigned rh2, rl2, ih2, il2, rh3, rl3, ih3, il3;
            split2(m0.x, m0.z, rh0, rl0); split2(m0.y, m0.w, ih0, il0);
            split2(m1.x, m1.z, rh1, rl1); split2(m1.y, m1.w, ih1, il1);
            split2(m2.x, m2.z, rh2, rl2); split2(m2.y, m2.w, ih2, il2);
            split2(m3.x, m3.z, rh3, rl3); split2(m3.y, m3.w, ih3, il3);
            const int idx = mi * 40 + mj8;
            *(uint4*)&MP[0][idx] = make_uint4(rh0, rh1, rh2, rh3);
            *(uint4*)&MP[1][idx] = make_uint4(rl0, rl1, rl2, rl3);
            *(uint4*)&MP[2][idx] = make_uint4(ih0, ih1, ih2, ih3);
            *(uint4*)&MP[3][idx] = make_uint4(il0, il1, il2, il3);
        }
        // ---- stage u^T: 64 kcol x 32 j, uint stores (2-way free)
        {
            const int j0 = 2 * ujp;
            const size_t o0 = GADDR(jb + j0,     kb0 + 4 * uq);
            const size_t o1 = GADDR(jb + j0 + 1, kb0 + 4 * uq);
            const float4 R0 = *(const float4*)(srcR + o0);
            const float4 R1 = *(const float4*)(srcR + o1);
            const float4 I0 = *(const float4*)(srcI + o0);
            const float4 I1 = *(const float4*)(srcI + o1);
            #pragma unroll
            for (int c = 0; c < 4; c++) {
                const int kc  = 4 * uq + c;
                const int idx = kc * 40 + j0;
                unsigned hh, ll;
                split2(f4c(R0, c), f4c(R1, c), hh, ll);
                *(unsigned*)&UP[0][idx] = hh;
                *(unsigned*)&UP[1][idx] = ll;
                split2(f4c(I0, c), f4c(I1, c), hh, ll);
                *(unsigned*)&UP[2][idx] = hh;
                *(unsigned*)&UP[3][idx] = ll;
            }
        }
        __syncthreads();

        // a = u^T rows (kcol), b = M rows (i); na = -(u imag)
        sh8 a[2][4], na[2][2], bfr[2][4];
        #pragma unroll
        for (int s = 0; s < 2; s++) {
            const int row = wr * 32 + s * 16 + frow;
            #pragma unroll
            for (int p = 0; p < 4; p++) a[s][p] = ldfrag40(&UP[p][0], row, kg);
            na[s][0] = a[s][2] ^ SGN;
            na[s][1] = a[s][3] ^ SGN;
        }
        #pragma unroll
        for (int s = 0; s < 2; s++) {
            const int row = wc * 32 + s * 16 + frow;
            #pragma unroll
            for (int p = 0; p < 4; p++) bfr[s][p] = ldfrag40(&MP[p][0], row, kg);
        }

        #pragma unroll
        for (int sr = 0; sr < 2; sr++) {
            #pragma unroll
            for (int sc = 0; sc < 2; sc++) {
                f32x4 r = gr[sr][sc], q = gi[sr][sc];
                // Dr = Ur*Mr - Ui*Mi (split HH+HL+LH)
                r = MFMA16(a[sr][0],  bfr[sc][0], r);
                r = MFMA16(a[sr][0],  bfr[sc][1], r);
                r = MFMA16(a[sr][1],  bfr[sc][0], r);
                r = MFMA16(na[sr][0], bfr[sc][2], r);
                r = MFMA16(na[sr][0], bfr[sc][3], r);
                r = MFMA16(na[sr][1], bfr[sc][2], r);
                // Di = Ur*Mi + Ui*Mr
                q = MFMA16(a[sr][0],  bfr[sc][2], q);
                q = MFMA16(a[sr][0],  bfr[sc][3], q);
                q = MFMA16(a[sr][1],  bfr[sc][2], q);
                q = MFMA16(a[sr][2],  bfr[sc][0], q);
                q = MFMA16(a[sr][2],  bfr[sc][1], q);
                q = MFMA16(a[sr][3],  bfr[sc][0], q);
                gr[sr][sc] = r; gi[sr][sc] = q;
            }
        }
        __syncthreads();
    }

    // epilogue: lane holds 4 consecutive k (rows) at one i (col) -> float4
    #pragma unroll
    for (int sr = 0; sr < 2; sr++)
        #pragma unroll
        for (int sc = 0; sc < 2; sc++) {
            const int k = kb0 + wr * 32 + sr * 16 + 4 * (lane >> 4);
            const int i = it  + wc * 32 + sc * 16 + (lane & 15);
            const size_t o = boff + (size_t)i * SI_ +
                (size_t)(k >> KL2_) * SKH_ + (size_t)(k & ((1 << KL2_) - 1));
            *(float4*)(dstR + o) = make_float4(gr[sr][sc][0], gr[sr][sc][1],
                                               gr[sr][sc][2], gr[sr][sc][3]);
            *(float4*)(dstI + o) = make_float4(gi[sr][sc][0], gi[sr][sc][1],
                                               gi[sr][sc][2], gi[sr][sc][3]);
        }
    #undef GADDR
}

// =====================================================================
// mix64_mfma (mode 2, d=64): u(b,j,k) = boff + j + (k&127)*64 + (k>>7)*8192.
// A = M (rows=i), B = u^T (rows=kcol) => D rows = i: lane holds 4
// consecutive i => float4 epilogue on contiguous i axis. j contiguous in
// memory => u^T staging reads float4 along j, writes uint2 (bank-floor).
// =====================================================================
__global__ __launch_bounds__(256, 3)
void mix64_mfma_kernel(const float* __restrict__ srcR, const float* __restrict__ srcI,
                       const float2* __restrict__ M,
                       float* __restrict__ dstR, float* __restrict__ dstI)
{
    const int kb0 = blockIdx.x << 6;   // 64-wide k tile
    const int b   = blockIdx.y;

    const int t    = threadIdx.x;
    const int lane = t & 63;
    const int wave = t >> 6;
    const int wr = wave & 1, wc = wave >> 1;   // wr: i half, wc: k half

    __shared__ unsigned short UP[4][2560];   // u^T planes [kcol][j 0..31], pitch 40
    __shared__ unsigned short MP[4][2560];   // M   planes [i   ][j 0..31], pitch 40

    const sh8 SGN = {(short)0x8000, (short)0x8000, (short)0x8000, (short)0x8000,
                     (short)0x8000, (short)0x8000, (short)0x8000, (short)0x8000};

    f32x4 gr[2][2], gi[2][2];     // [sr: i-sub][sc: k-sub]
    const f32x4 z4 = {0.f, 0.f, 0.f, 0.f};
    #pragma unroll
    for (int x = 0; x < 2; x++)
        #pragma unroll
        for (int y = 0; y < 2; y++) { gr[x][y] = z4; gi[x][y] = z4; }

    const size_t boff  = (size_t)b * SSIZE;
    const float2* Mb   = M + (size_t)b * 64 * 64;
    const size_t koffb = (size_t)(kb0 & 127) * 64 + (size_t)(kb0 >> 7) * 8192;

    // staging maps
    const int mi  = t >> 2;        // i row for M
    const int mj8 = (t & 3) * 8;   // j octet for M
    const int ujq = t & 7;         // j quad: j0 = 4*ujq
    const int ukc = t >> 3;        // kcol 0..31 (+32 second item)

    const int frow = lane & 15;
    const int kg   = lane >> 4;

    for (int jt = 0; jt < 2; jt++) {
        const int jb = jt * 32;
        // ---- stage M: 64 i x 32 j (row stride 64 complex)
        {
            const float2* mp = &Mb[(size_t)mi * 64 + jb + mj8];
            const float4 m0 = *(const float4*)(mp);
            const float4 m1 = *(const float4*)(mp + 2);
            const float4 m2 = *(const float4*)(mp + 4);
            const float4 m3 = *(const float4*)(mp + 6);
            unsigned rh0, rl0, ih0, il0, rh1, rl1, ih1, il1;
            unsigned rh2, rl2, ih2, il2, rh3, rl3, ih3, il3;
            split2(m0.x, m0.z, rh0, rl0); split2(m0.y, m0.w, ih0, il0);
            split2(m1.x, m1.z, rh1, rl1); split2(m1.y, m1.w, ih1, il1);
            split2(m2.x, m2.z, rh2, rl2); split2(m2.y, m2.w, ih2, il2);
            split2(m3.x, m3.z, rh3, rl3); split2(m3.y, m3.w, ih3, il3);
            const int idx = mi * 40 + mj8;
            *(uint4*)&MP[0][idx] = make_uint4(rh0, rh1, rh2, rh3);
            *(uint4*)&MP[1][idx] = make_uint4(rl0, rl1, rl2, rl3);
            *(uint4*)&MP[2][idx] = make_uint4(ih0, ih1, ih2, ih3);
            *(uint4*)&MP[3][idx] = make_uint4(il0, il1, il2, il3);
        }
        // ---- stage u^T: 64 kcol x 32 j, j contiguous in memory
        #pragma unroll
        for (int m = 0; m < 2; m++) {
            const int kc = ukc + 32 * m;
            const size_t o = boff + koffb + (size_t)kc * 64 + jb + 4 * ujq;
            const float4 R = *(const float4*)(srcR + o);
            const float4 I = *(const float4*)(srcI + o);
            const int idx = kc * 40 + 4 * ujq;
            unsigned h0, l0, h1, l1;
            split2(R.x, R.y, h0, l0); split2(R.z, R.w, h1, l1);
            *(uint2*)&UP[0][idx] = make_uint2(h0, h1);
            *(uint2*)&UP[1][idx] = make_uint2(l0, l1);
            split2(I.x, I.y, h0, l0); split2(I.z, I.w, h1, l1);
            *(uint2*)&UP[2][idx] = make_uint2(h0, h1);
            *(uint2*)&UP[3][idx] = make_uint2(l0, l1);
        }
        __syncthreads();

        // a = M rows (i), b = u^T rows (kcol); na = -(M imag)
        sh8 a[2][4], na[2][2], bfr[2][4];
        #pragma unroll
        for (int s = 0; s < 2; s++) {
            const int row = wr * 32 + s * 16 + frow;
            #pragma unroll
            for (int p = 0; p < 4; p++) a[s][p] = ldfrag40(&MP[p][0], row, kg);
            na[s][0] = a[s][2] ^ SGN;
            na[s][1] = a[s][3] ^ SGN;
        }
        #pragma unroll
        for (int s = 0; s < 2; s++) {
            const int row = wc * 32 + s * 16 + frow;
            #pragma unroll
            for (int p = 0; p < 4; p++) bfr[s][p] = ldfrag40(&UP[p][0], row, kg);
        }

        #pragma unroll
        for (int sr = 0; sr < 2; sr++) {
            #pragma unroll
            for (int sc = 0; sc < 2; sc++) {
                f32x4 r = gr[sr][sc], q = gi[sr][sc];
                r = MFMA16(a[sr][0],  bfr[sc][0], r);
                r = MFMA16(a[sr][0],  bfr[sc][1], r);
                r = MFMA16(a[sr][1],  bfr[sc][0], r);
                r = MFMA16(na[sr][0], bfr[sc][2], r);
                r = MFMA16(na[sr][0], bfr[sc][3], r);
                r = MFMA16(na[sr][1], bfr[sc][2], r);
                q = MFMA16(a[sr][0],  bfr[sc][2], q);
                q = MFMA16(a[sr][0],  bfr[sc][3], q);
                q = MFMA16(a[sr][1],  bfr[sc][2], q);
                q = MFMA16(a[sr][2],  bfr[sc][0], q);
                q = MFMA16(a[sr][2],  bfr[sc][1], q);
                q = MFMA16(a[sr][3],  bfr[sc][0], q);
                gr[sr][sc] = r; gi[sr][sc] = q;
            }
        }
        __syncthreads();
    }

    // epilogue: lane holds 4 consecutive i (rows) at one kcol (col) -> float4
    #pragma unroll
    for (int sr = 0; sr < 2; sr++)
        #pragma unroll
        for (int sc = 0; sc < 2; sc++) {
            const int i  = wr * 32 + sr * 16 + 4 * (lane >> 4);
            const int kc = wc * 32 + sc * 16 + (lane & 15);
            const size_t o = boff + koffb + (size_t)kc * 64 + i;
            *(float4*)(dstR + o) = make_float4(gr[sr][sc][0], gr[sr][sc][1],
                                               gr[sr][sc][2], gr[sr][sc][3]);
            *(float4*)(dstI + o) = make_float4(gi[sr][sc][0], gi[sr][sc][1],
                                               gi[sr][sc][2], gi[sr][sc][3]);
        }
}

extern "C" void kernel_launch(void* const* d_in, const int* in_sizes, int n_in,
                              void* d_out, int out_size, void* d_ws, size_t ws_size,
                              hipStream_t stream)
{
    const float* xr  = (const float*)d_in[0];
    const float* xi  = (const float*)d_in[1];
    const float* w0r = (const float*)d_in[2];
    const float* w0i = (const float*)d_in[3];
    const float* w1r = (const float*)d_in[4];
    const float* w1i = (const float*)d_in[5];
    const float* w2r = (const float*)d_in[6];
    const float* w2i = (const float*)d_in[7];
    const float* lt  = (const float*)d_in[8];

    float* outR = (float*)d_out;
    float* outI = outR + (size_t)BATCH * SSIZE;

    float*  wsR = (float*)d_ws;
    float*  wsI = wsR + (size_t)BATCH * SSIZE;
    float*  Gf  = wsI + (size_t)BATCH * SSIZE;
    float2* Mf  = (float2*)(Gf + (size_t)BATCH * 128 * 128 * 2);

    // Partial slabs live in DEAD buffer phases (no extra workspace):
    //  mode 0: outR; mode 1: wsR; mode 2: outR. (See R9 notes.)

    // ---------------- mode 0: d=128, SI=8192, KL2=13
    gram_mfma_kernel<8192, 13, 0><<<dim3(3, 16, BATCH), 256, 0, stream>>>(xr, xi, outR, 512);
    reduce_kernel<16, 8192><<<dim3(256), 256, 0, stream>>>((const float4*)outR, (float4*)Gf);
    score_kernel<<<dim3(128, BATCH), 128, 0, stream>>>(Gf, w0r, w0i, lt, Mf, 128);
    mix128_mfma_kernel<8192, 13, 0><<<dim3(128, 2, BATCH), 256, 0, stream>>>(xr, xi, Mf, outR, outI);

    // ---------------- mode 1: d=128, SI=64, KL2=6, SKH=8192
    gram_mfma_kernel<64, 6, 8192><<<dim3(3, 16, BATCH), 256, 0, stream>>>(outR, outI, wsR, 512);
    reduce_kernel<16, 8192><<<dim3(256), 256, 0, stream>>>((const float4*)wsR, (float4*)Gf);
    score_kernel<<<dim3(128, BATCH), 128, 0, stream>>>(Gf, w1r, w1i, lt, Mf, 128);
    mix128_mfma_kernel<64, 6, 8192><<<dim3(128, 2, BATCH), 256, 0, stream>>>(outR, outI, Mf, wsR, wsI);

    // ---------------- mode 2: d=64, SI=1, k: (k&127)*64 + (k>>7)*8192
    gram64_mfma_kernel<<<dim3(32, BATCH), 256, 0, stream>>>(wsR, wsI, outR, 512);
    reduce_kernel<32, 2048><<<dim3(64), 256, 0, stream>>>((const float4*)outR, (float4*)Gf);
    score_kernel<<<dim3(64, BATCH), 64, 0, stream>>>(Gf, w2r, w2i, lt, Mf, 64);
    mix64_mfma_kernel<<<dim3(256, BATCH), 256, 0, stream>>>(wsR, wsI, Mf, outR, outI);
}

// Round 7
// 426.739 us; speedup vs baseline: 2.1872x; 1.0472x over previous
//
#include <hip/hip_runtime.h>
#include <math.h>

#define BATCH 8
#define SSIZE 1048576   // 128*128*64

// R11 (resubmit R13): occupancy round (R4 counters: gram_mfma all pipes <17%,
// Occupancy 11.6%, grid 384 = 1.5 blocks/CU => latency-bound). k-splits:
// gram_mfma NS=32 (768 blocks = exactly 3/CU), gram64 NS=128 + lb(256,4)
// (1024 blocks = 4/CU). Partial slabs span contiguous dead R+I pairs
// (64 MB) => still zero extra workspace. Math/kernels otherwise identical
// to R4 (446.9us, absmax 3.05e-5). Twice re-audited (R5, R6): grids, slab
// bounds, buffer lifetimes, reduce coverage, lb legality, k-split traffic.

typedef short sh8 __attribute__((ext_vector_type(8)));
typedef float f32x4 __attribute__((ext_vector_type(4)));

#define MFMA16(a, b, c) __builtin_amdgcn_mfma_f32_16x16x32_bf16((a), (b), (c), 0, 0, 0)

__device__ __forceinline__ unsigned short bf_rne(float x) {
    unsigned u = __float_as_uint(x);
    unsigned r = u + 0x7fffu + ((u >> 16) & 1u);
    return (unsigned short)(r >> 16);
}

// split x into hi + lo bf16 (both RNE)
__device__ __forceinline__ void split1(float x, unsigned short &h, unsigned short &l) {
    h = bf_rne(x);
    float hf = __uint_as_float((unsigned)h << 16);
    l = bf_rne(x - hf);
}

// split two floats, pack hi pair / lo pair as u32 (a in low 16, b in high)
__device__ __forceinline__ void split2(float a, float b, unsigned &hh, unsigned &ll) {
    unsigned short ha = bf_rne(a), hb = bf_rne(b);
    hh = (unsigned)ha | ((unsigned)hb << 16);
    float ra = a - __uint_as_float((unsigned)ha << 16);
    float rb = b - __uint_as_float((unsigned)hb << 16);
    ll = (unsigned)bf_rne(ra) | ((unsigned)bf_rne(rb) << 16);
}

__device__ __forceinline__ float f4c(const float4 &v, int c) {
    return c == 0 ? v.x : c == 1 ? v.y : c == 2 ? v.z : v.w;
}

// fragment load, pitch-32 planes with XOR swizzle (gram kernels, proven)
__device__ __forceinline__ sh8 ldfrag(const unsigned short *pl, int row, int kg) {
    const int idx = (row * 32 + kg * 8) ^ ((row & 3) << 3);
    return *(const sh8 *)(pl + idx);
}

// fragment load, pitch-40 planes, no swizzle (mix kernels; bank-optimal)
__device__ __forceinline__ sh8 ldfrag40(const unsigned short *pl, int row, int kg) {
    return *(const sh8 *)(pl + row * 40 + kg * 8);
}

// ---------------- partial-slab reduce: out[b][r] = sum_s in[b][s][r] --------
template<int NS, int PERB>   // PERB in float4 units
__global__ __launch_bounds__(256)
void reduce_kernel(const float4* __restrict__ in, float4* __restrict__ out) {
    const int gid = blockIdx.x * blockDim.x + threadIdx.x;
    const int b = gid / PERB, r = gid - b * PERB;
    const float4* p = in + (size_t)b * NS * PERB + r;
    float4 a = p[0];
    #pragma unroll 8
    for (int s = 1; s < NS; s++) {
        const float4 v = p[(size_t)s * PERB];
        a.x += v.x; a.y += v.y; a.z += v.z; a.w += v.w;
    }
    out[gid] = a;
}

// =====================================================================
// gram_mfma (modes 0/1, d=128): G = u u^T, symmetric. (R4-proven body.)
// =====================================================================
template<int SI_, int KL2_, int SKH_>
__global__ __launch_bounds__(256, 3)
void gram_mfma_kernel(const float* __restrict__ srcR, const float* __restrict__ srcI,
                      float* __restrict__ Gp, int kPerBlock)
{
    const int tile = blockIdx.x;             // 0,1,2
    const int it = (tile == 2) ? 64 : 0;
    const int jt = (tile == 0) ? 0 : 64;
    const bool diag = (it == jt);
    const int b  = blockIdx.z;
    const int k0 = blockIdx.y * kPerBlock;

    const int t    = threadIdx.x;
    const int lane = t & 63;
    const int wave = t >> 6;          // 0..3
    const int wr = wave & 1, wc = wave >> 1;

    __shared__ unsigned short SA[4][2048];   // planes rH,rL,iH,iL  [64 rows][32 k]
    __shared__ unsigned short SB[4][2048];

    const sh8 SGN = {(short)0x8000, (short)0x8000, (short)0x8000, (short)0x8000,
                     (short)0x8000, (short)0x8000, (short)0x8000, (short)0x8000};

    f32x4 gr[2][2], gi[2][2];
    const f32x4 z4 = {0.f, 0.f, 0.f, 0.f};
    #pragma unroll
    for (int x = 0; x < 2; x++)
        #pragma unroll
        for (int y = 0; y < 2; y++) { gr[x][y] = z4; gi[x][y] = z4; }

    const size_t boff = (size_t)b * SSIZE;
    const int nT = kPerBlock >> 5;

    const int kq   = t & 7;
    const int row2 = t >> 3;

    const int frow = lane & 15;
    const int kg   = lane >> 4;

    #define GADDR(ii, k) (boff + (size_t)(ii) * SI_ + \
        (size_t)((k) >> KL2_) * SKH_ + (size_t)((k) & ((1 << KL2_) - 1)))

    for (int kt = 0; kt < nT; kt++) {
        const int kb = k0 + kt * 32;
        #pragma unroll
        for (int m = 0; m < 2; m++) {
            const int row = row2 + 32 * m;
            const int idx = (row * 32 + kq * 4) ^ ((row & 3) << 3);
            {
                const size_t off = GADDR(it + row, kb + kq * 4);
                const float4 R = *(const float4*)(srcR + off);
                const float4 I = *(const float4*)(srcI + off);
                ushort4 rh, rl, ih, il;
                split1(R.x, rh.x, rl.x); split1(R.y, rh.y, rl.y);
                split1(R.z, rh.z, rl.z); split1(R.w, rh.w, rl.w);
                split1(I.x, ih.x, il.x); split1(I.y, ih.y, il.y);
                split1(I.z, ih.z, il.z); split1(I.w, ih.w, il.w);
                *(ushort4*)&SA[0][idx] = rh;
                *(ushort4*)&SA[1][idx] = rl;
                *(ushort4*)&SA[2][idx] = ih;
                *(ushort4*)&SA[3][idx] = il;
            }
            if (!diag) {
                const size_t off = GADDR(jt + row, kb + kq * 4);
                const float4 R = *(const float4*)(srcR + off);
                const float4 I = *(const float4*)(srcI + off);
                ushort4 rh, rl, ih, il;
                split1(R.x, rh.x, rl.x); split1(R.y, rh.y, rl.y);
                split1(R.z, rh.z, rl.z); split1(R.w, rh.w, rl.w);
                split1(I.x, ih.x, il.x); split1(I.y, ih.y, il.y);
                split1(I.z, ih.z, il.z); split1(I.w, ih.w, il.w);
                *(ushort4*)&SB[0][idx] = rh;
                *(ushort4*)&SB[1][idx] = rl;
                *(ushort4*)&SB[2][idx] = ih;
                *(ushort4*)&SB[3][idx] = il;
            }
        }
        __syncthreads();

        unsigned short (*BP)[2048] = diag ? SA : SB;

        sh8 a[2][4], na[2][2], bfr[2][4];
        #pragma unroll
        for (int s = 0; s < 2; s++) {
            const int row = wr * 32 + s * 16 + frow;
            #pragma unroll
            for (int p = 0; p < 4; p++) a[s][p] = ldfrag(&SA[p][0], row, kg);
            na[s][0] = a[s][2] ^ SGN;
            na[s][1] = a[s][3] ^ SGN;
        }
        #pragma unroll
        for (int s = 0; s < 2; s++) {
            const int row = wc * 32 + s * 16 + frow;
            #pragma unroll
            for (int p = 0; p < 4; p++) bfr[s][p] = ldfrag(&BP[p][0], row, kg);
        }

        #pragma unroll
        for (int sr = 0; sr < 2; sr++) {
            #pragma unroll
            for (int sc = 0; sc < 2; sc++) {
                f32x4 r = gr[sr][sc], q = gi[sr][sc];
                r = MFMA16(a[sr][0],  bfr[sc][0], r);
                r = MFMA16(a[sr][0],  bfr[sc][1], r);
                r = MFMA16(a[sr][1],  bfr[sc][0], r);
                r = MFMA16(na[sr][0], bfr[sc][2], r);
                r = MFMA16(na[sr][0], bfr[sc][3], r);
                r = MFMA16(na[sr][1], bfr[sc][2], r);
                q = MFMA16(a[sr][0],  bfr[sc][2], q);
                q = MFMA16(a[sr][0],  bfr[sc][3], q);
                q = MFMA16(a[sr][1],  bfr[sc][2], q);
                q = MFMA16(a[sr][2],  bfr[sc][0], q);
                q = MFMA16(a[sr][2],  bfr[sc][1], q);
                q = MFMA16(a[sr][3],  bfr[sc][0], q);
                gr[sr][sc] = r; gi[sr][sc] = q;
            }
        }
        __syncthreads();
    }
    #undef GADDR

    float* Gb = Gp + ((size_t)b * gridDim.y + blockIdx.y) * (128 * 128 * 2);
    const int rb   = (lane >> 4) * 4;
    const int jcol = lane & 15;
    #pragma unroll
    for (int sr = 0; sr < 2; sr++)
        #pragma unroll
        for (int sc = 0; sc < 2; sc++)
            #pragma unroll
            for (int r = 0; r < 4; r++) {
                const int i = it + wr * 32 + sr * 16 + rb + r;
                const int j = jt + wc * 32 + sc * 16 + jcol;
                const float vr = gr[sr][sc][r], vi = gi[sr][sc][r];
                *(float2*)&Gb[(i * 128 + j) * 2] = make_float2(vr, vi);
                if (!diag)
                    *(float2*)&Gb[(j * 128 + i) * 2] = make_float2(vr, vi);
            }
}

// =====================================================================
// gram64_mfma (mode 2, d=64). R4-proven body; lb(256,4) for 4 blocks/CU.
// =====================================================================
__global__ __launch_bounds__(256, 4)
void gram64_mfma_kernel(const float* __restrict__ srcR, const float* __restrict__ srcI,
                        float* __restrict__ Gp, int kPerBlock)
{
    const int b  = blockIdx.y;
    const int k0 = blockIdx.x * kPerBlock;

    const int t    = threadIdx.x;
    const int lane = t & 63;
    const int wave = t >> 6;
    const int wr = wave & 1, wc = wave >> 1;

    __shared__ unsigned short SA[4][2048];   // planes [64 i][32 k]

    const sh8 SGN = {(short)0x8000, (short)0x8000, (short)0x8000, (short)0x8000,
                     (short)0x8000, (short)0x8000, (short)0x8000, (short)0x8000};

    f32x4 gr[2][2], gi[2][2];
    const f32x4 z4 = {0.f, 0.f, 0.f, 0.f};
    #pragma unroll
    for (int x = 0; x < 2; x++)
        #pragma unroll
        for (int y = 0; y < 2; y++) { gr[x][y] = z4; gi[x][y] = z4; }

    const size_t boff = (size_t)b * SSIZE;
    const int nT = kPerBlock >> 5;

    const int kp = t & 15;        // k = 2kp, 2kp+1 within tile
    const int i0 = (t >> 4) * 4;  // i quad

    const int frow = lane & 15;
    const int kg   = lane >> 4;

    for (int kt = 0; kt < nT; kt++) {
        const int kb = k0 + kt * 32;
        const int ke = kb + 2 * kp;
        const int ko = ke + 1;
        const size_t offE = boff + (size_t)(ke & 127) * 64 + (size_t)(ke >> 7) * 8192 + i0;
        const size_t offO = boff + (size_t)(ko & 127) * 64 + (size_t)(ko >> 7) * 8192 + i0;
        const float4 R0 = *(const float4*)(srcR + offE);
        const float4 I0 = *(const float4*)(srcI + offE);
        const float4 R1 = *(const float4*)(srcR + offO);
        const float4 I1 = *(const float4*)(srcI + offO);
        const int kw = 2 * kp;
        #pragma unroll
        for (int c = 0; c < 4; c++) {
            const int i   = i0 + c;
            const int idx = (i * 32 + kw) ^ ((i & 3) << 3);
            unsigned short h0, l0, h1, l1;
            split1(f4c(R0, c), h0, l0);
            split1(f4c(R1, c), h1, l1);
            *(ushort2*)&SA[0][idx] = make_ushort2(h0, h1);
            *(ushort2*)&SA[1][idx] = make_ushort2(l0, l1);
            split1(f4c(I0, c), h0, l0);
            split1(f4c(I1, c), h1, l1);
            *(ushort2*)&SA[2][idx] = make_ushort2(h0, h1);
            *(ushort2*)&SA[3][idx] = make_ushort2(l0, l1);
        }
        __syncthreads();

        sh8 a[2][4], na[2][2], bfr[2][4];
        #pragma unroll
        for (int s = 0; s < 2; s++) {
            const int row = wr * 32 + s * 16 + frow;
            #pragma unroll
            for (int p = 0; p < 4; p++) a[s][p] = ldfrag(&SA[p][0], row, kg);
            na[s][0] = a[s][2] ^ SGN;
            na[s][1] = a[s][3] ^ SGN;
        }
        #pragma unroll
        for (int s = 0; s < 2; s++) {
            const int row = wc * 32 + s * 16 + frow;
            #pragma unroll
            for (int p = 0; p < 4; p++) bfr[s][p] = ldfrag(&SA[p][0], row, kg);
        }

        #pragma unroll
        for (int sr = 0; sr < 2; sr++) {
            #pragma unroll
            for (int sc = 0; sc < 2; sc++) {
                f32x4 r = gr[sr][sc], q = gi[sr][sc];
                r = MFMA16(a[sr][0],  bfr[sc][0], r);
                r = MFMA16(a[sr][0],  bfr[sc][1], r);
                r = MFMA16(a[sr][1],  bfr[sc][0], r);
                r = MFMA16(na[sr][0], bfr[sc][2], r);
                r = MFMA16(na[sr][0], bfr[sc][3], r);
                r = MFMA16(na[sr][1], bfr[sc][2], r);
                q = MFMA16(a[sr][0],  bfr[sc][2], q);
                q = MFMA16(a[sr][0],  bfr[sc][3], q);
                q = MFMA16(a[sr][1],  bfr[sc][2], q);
                q = MFMA16(a[sr][2],  bfr[sc][0], q);
                q = MFMA16(a[sr][2],  bfr[sc][1], q);
                q = MFMA16(a[sr][3],  bfr[sc][0], q);
                gr[sr][sc] = r; gi[sr][sc] = q;
            }
        }
        __syncthreads();
    }

    float* Gb = Gp + ((size_t)b * gridDim.x + blockIdx.x) * (64 * 64 * 2);
    const int rb   = (lane >> 4) * 4;
    const int jcol = lane & 15;
    #pragma unroll
    for (int sr = 0; sr < 2; sr++)
        #pragma unroll
        for (int sc = 0; sc < 2; sc++)
            #pragma unroll
            for (int r = 0; r < 4; r++) {
                const int i = wr * 32 + sr * 16 + rb + r;
                const int j = wc * 32 + sc * 16 + jcol;
                *(float2*)&Gb[(i * 64 + j) * 2] = make_float2(gr[sr][sc][r], gi[sr][sc][r]);
            }
}

// ---------------- score/softmax/phase -> routing matrix M ----------------
__global__ __launch_bounds__(128)
void score_kernel(const float* __restrict__ G,
                  const float* __restrict__ Wre, const float* __restrict__ Wim,
                  const float* __restrict__ log_tau,
                  float2* __restrict__ Mout, int d)
{
    const int b = blockIdx.y;
    const int i = blockIdx.x;
    const int j = threadIdx.x;

    const float2* Gb = (const float2*)G + (size_t)b * d * d;

    float sre = 0.f, sim = 0.f;
    for (int l = 0; l < d; l++) {
        float wr = Wre[i * d + l];
        float wi = Wim[i * d + l];
        float2 g = Gb[l * d + j];
        sre = fmaf(wr, g.x, sre);
        sre = fmaf(-wi, g.y, sre);
        sim = fmaf(wr, g.y, sim);
        sim = fmaf(wi, g.x, sim);
    }

    float mag = sqrtf(sre * sre + sim * sim);
    float tau = fmaxf(expf(log_tau[0]), 1e-8f);
    float scale = tau * sqrtf((float)SSIZE / (float)d);
    float mval = mag / scale;

    __shared__ float red[128];
    red[j] = mval;
    __syncthreads();
    for (int s = d >> 1; s > 0; s >>= 1) {
        if (j < s) red[j] = fmaxf(red[j], red[j + s]);
        __syncthreads();
    }
    float mx = red[0];
    __syncthreads();
    float e = expf(mval - mx);
    red[j] = e;
    __syncthreads();
    for (int s = d >> 1; s > 0; s >>= 1) {
        if (j < s) red[j] += red[j + s];
        __syncthreads();
    }
    float routing = e / red[0];

    float safe = fmaxf(mag, 1e-8f);
    float pre, pim;
    if (mag > 1e-8f) { pre = sre / safe; pim = sim / safe; }
    else             { pre = 1.f;       pim = 0.f; }

    Mout[(size_t)b * d * d + i * d + j] = make_float2(routing * pre, routing * pim);
}

// =====================================================================
// mix128_mfma (modes 0/1, d=128). Unchanged from R4 (proven).
// =====================================================================
template<int SI_, int KL2_, int SKH_>
__global__ __launch_bounds__(256, 3)
void mix128_mfma_kernel(const float* __restrict__ srcR, const float* __restrict__ srcI,
                        const float2* __restrict__ M,
                        float* __restrict__ dstR, float* __restrict__ dstI)
{
    const int kb0 = blockIdx.x << 6;   // 64-wide k tile
    const int it  = blockIdx.y << 6;   // 64-wide i tile
    const int b   = blockIdx.z;

    const int t    = threadIdx.x;
    const int lane = t & 63;
    const int wave = t >> 6;
    const int wr = wave & 1, wc = wave >> 1;   // wr: k half, wc: i half

    __shared__ unsigned short UP[4][2560];   // u^T planes [kcol 0..63][j 0..31], pitch 40
    __shared__ unsigned short MP[4][2560];   // M   planes [i    0..63][j 0..31], pitch 40

    const sh8 SGN = {(short)0x8000, (short)0x8000, (short)0x8000, (short)0x8000,
                     (short)0x8000, (short)0x8000, (short)0x8000, (short)0x8000};

    f32x4 gr[2][2], gi[2][2];     // [sr: k-sub][sc: i-sub]
    const f32x4 z4 = {0.f, 0.f, 0.f, 0.f};
    #pragma unroll
    for (int x = 0; x < 2; x++)
        #pragma unroll
        for (int y = 0; y < 2; y++) { gr[x][y] = z4; gi[x][y] = z4; }

    const size_t boff = (size_t)b * SSIZE;
    const float2* Mb  = M + (size_t)b * 128 * 128;

    #define GADDR(jj, k) (boff + (size_t)(jj) * SI_ + \
        (size_t)((k) >> KL2_) * SKH_ + (size_t)((k) & ((1 << KL2_) - 1)))

    // staging maps
    const int ujp = t & 15;        // j pair: j0 = 2*ujp
    const int uq  = t >> 4;        // k quad: kc0 = 4*uq
    const int mi  = t >> 2;        // i row for M
    const int mj8 = (t & 3) * 8;   // j octet for M

    const int frow = lane & 15;
    const int kg   = lane >> 4;

    for (int jt = 0; jt < 4; jt++) {
        const int jb = jt * 32;
        // ---- stage M: 64 i x 32 j, 4 planes, uint4 stores
        {
            const float2* mp = &Mb[(size_t)(it + mi) * 128 + jb + mj8];
            const float4 m0 = *(const float4*)(mp);
            const float4 m1 = *(const float4*)(mp + 2);
            const float4 m2 = *(const float4*)(mp + 4);
            const float4 m3 = *(const float4*)(mp + 6);
            unsigned rh0, rl0, ih0, il0, rh1, rl1, ih1, il1;
            unsigned rh2, rl2, ih2, il2, rh3, rl3, ih3, il3;
            split2(m0.x, m0.z, rh0, rl0); split2(m0.y, m0.w, ih0, il0);
            split2(m1.x, m1.z, rh1, rl1); split2(m1.y, m1.w, ih1, il1);
            split2(m2.x, m2.z, rh2, rl2); split2(m2.y, m2.w, ih2, il2);
            split2(m3.x, m3.z, rh3, rl3); split2(m3.y, m3.w, ih3, il3);
            const int idx = mi * 40 + mj8;
            *(uint4*)&MP[0][idx] = make_uint4(rh0, rh1, rh2, rh3);
            *(uint4*)&MP[1][idx] = make_uint4(rl0, rl1, rl2, rl3);
            *(uint4*)&MP[2][idx] = make_uint4(ih0, ih1, ih2, ih3);
            *(uint4*)&MP[3][idx] = make_uint4(il0, il1, il2, il3);
        }
        // ---- stage u^T: 64 kcol x 32 j, uint stores
        {
            const int j0 = 2 * ujp;
            const size_t o0 = GADDR(jb + j0,     kb0 + 4 * uq);
            const size_t o1 = GADDR(jb + j0 + 1, kb0 + 4 * uq);
            const float4 R0 = *(const float4*)(srcR + o0);
            const float4 R1 = *(const float4*)(srcR + o1);
            const float4 I0 = *(const float4*)(srcI + o0);
            const float4 I1 = *(const float4*)(srcI + o1);
            #pragma unroll
            for (int c = 0; c < 4; c++) {
                const int kc  = 4 * uq + c;
                const int idx = kc * 40 + j0;
                unsigned hh, ll;
                split2(f4c(R0, c), f4c(R1, c), hh, ll);
                *(unsigned*)&UP[0][idx] = hh;
                *(unsigned*)&UP[1][idx] = ll;
                split2(f4c(I0, c), f4c(I1, c), hh, ll);
                *(unsigned*)&UP[2][idx] = hh;
                *(unsigned*)&UP[3][idx] = ll;
            }
        }
        __syncthreads();

        sh8 a[2][4], na[2][2], bfr[2][4];
        #pragma unroll
        for (int s = 0; s < 2; s++) {
            const int row = wr * 32 + s * 16 + frow;
            #pragma unroll
            for (int p = 0; p < 4; p++) a[s][p] = ldfrag40(&UP[p][0], row, kg);
            na[s][0] = a[s][2] ^ SGN;
            na[s][1] = a[s][3] ^ SGN;
        }
        #pragma unroll
        for (int s = 0; s < 2; s++) {
            const int row = wc * 32 + s * 16 + frow;
            #pragma unroll
            for (int p = 0; p < 4; p++) bfr[s][p] = ldfrag40(&MP[p][0], row, kg);
        }

        #pragma unroll
        for (int sr = 0; sr < 2; sr++) {
            #pragma unroll
            for (int sc = 0; sc < 2; sc++) {
                f32x4 r = gr[sr][sc], q = gi[sr][sc];
                r = MFMA16(a[sr][0],  bfr[sc][0], r);
                r = MFMA16(a[sr][0],  bfr[sc][1], r);
                r = MFMA16(a[sr][1],  bfr[sc][0], r);
                r = MFMA16(na[sr][0], bfr[sc][2], r);
                r = MFMA16(na[sr][0], bfr[sc][3], r);
                r = MFMA16(na[sr][1], bfr[sc][2], r);
                q = MFMA16(a[sr][0],  bfr[sc][2], q);
                q = MFMA16(a[sr][0],  bfr[sc][3], q);
                q = MFMA16(a[sr][1],  bfr[sc][2], q);
                q = MFMA16(a[sr][2],  bfr[sc][0], q);
                q = MFMA16(a[sr][2],  bfr[sc][1], q);
                q = MFMA16(a[sr][3],  bfr[sc][0], q);
                gr[sr][sc] = r; gi[sr][sc] = q;
            }
        }
        __syncthreads();
    }

    // epilogue: lane holds 4 consecutive k (rows) at one i (col) -> float4
    #pragma unroll
    for (int sr = 0; sr < 2; sr++)
        #pragma unroll
        for (int sc = 0; sc < 2; sc++) {
            const int k = kb0 + wr * 32 + sr * 16 + 4 * (lane >> 4);
            const int i = it  + wc * 32 + sc * 16 + (lane & 15);
            const size_t o = boff + (size_t)i * SI_ +
                (size_t)(k >> KL2_) * SKH_ + (size_t)(k & ((1 << KL2_) - 1));
            *(float4*)(dstR + o) = make_float4(gr[sr][sc][0], gr[sr][sc][1],
                                               gr[sr][sc][2], gr[sr][sc][3]);
            *(float4*)(dstI + o) = make_float4(gi[sr][sc][0], gi[sr][sc][1],
                                               gi[sr][sc][2], gi[sr][sc][3]);
        }
    #undef GADDR
}

// =====================================================================
// mix64_mfma (mode 2, d=64). Unchanged from R4 (proven).
// =====================================================================
__global__ __launch_bounds__(256, 3)
void mix64_mfma_kernel(const float* __restrict__ srcR, const float* __restrict__ srcI,
                       const float2* __restrict__ M,
                       float* __restrict__ dstR, float* __restrict__ dstI)
{
    const int kb0 = blockIdx.x << 6;   // 64-wide k tile
    const int b   = blockIdx.y;

    const int t    = threadIdx.x;
    const int lane = t & 63;
    const int wave = t >> 6;
    const int wr = wave & 1, wc = wave >> 1;   // wr: i half, wc: k half

    __shared__ unsigned short UP[4][2560];   // u^T planes [kcol][j 0..31], pitch 40
    __shared__ unsigned short MP[4][2560];   // M   planes [i   ][j 0..31], pitch 40

    const sh8 SGN = {(short)0x8000, (short)0x8000, (short)0x8000, (short)0x8000,
                     (short)0x8000, (short)0x8000, (short)0x8000, (short)0x8000};

    f32x4 gr[2][2], gi[2][2];     // [sr: i-sub][sc: k-sub]
    const f32x4 z4 = {0.f, 0.f, 0.f, 0.f};
    #pragma unroll
    for (int x = 0; x < 2; x++)
        #pragma unroll
        for (int y = 0; y < 2; y++) { gr[x][y] = z4; gi[x][y] = z4; }

    const size_t boff  = (size_t)b * SSIZE;
    const float2* Mb   = M + (size_t)b * 64 * 64;
    const size_t koffb = (size_t)(kb0 & 127) * 64 + (size_t)(kb0 >> 7) * 8192;

    // staging maps
    const int mi  = t >> 2;        // i row for M
    const int mj8 = (t & 3) * 8;   // j octet for M
    const int ujq = t & 7;         // j quad: j0 = 4*ujq
    const int ukc = t >> 3;        // kcol 0..31 (+32 second item)

    const int frow = lane & 15;
    const int kg   = lane >> 4;

    for (int jt = 0; jt < 2; jt++) {
        const int jb = jt * 32;
        // ---- stage M: 64 i x 32 j (row stride 64 complex)
        {
            const float2* mp = &Mb[(size_t)mi * 64 + jb + mj8];
            const float4 m0 = *(const float4*)(mp);
            const float4 m1 = *(const float4*)(mp + 2);
            const float4 m2 = *(const float4*)(mp + 4);
            const float4 m3 = *(const float4*)(mp + 6);
            unsigned rh0, rl0, ih0, il0, rh1, rl1, ih1, il1;
            unsigned rh2, rl2, ih2, il2, rh3, rl3, ih3, il3;
            split2(m0.x, m0.z, rh0, rl0); split2(m0.y, m0.w, ih0, il0);
            split2(m1.x, m1.z, rh1, rl1); split2(m1.y, m1.w, ih1, il1);
            split2(m2.x, m2.z, rh2, rl2); split2(m2.y, m2.w, ih2, il2);
            split2(m3.x, m3.z, rh3, rl3); split2(m3.y, m3.w, ih3, il3);
            const int idx = mi * 40 + mj8;
            *(uint4*)&MP[0][idx] = make_uint4(rh0, rh1, rh2, rh3);
            *(uint4*)&MP[1][idx] = make_uint4(rl0, rl1, rl2, rl3);
            *(uint4*)&MP[2][idx] = make_uint4(ih0, ih1, ih2, ih3);
            *(uint4*)&MP[3][idx] = make_uint4(il0, il1, il2, il3);
        }
        // ---- stage u^T: 64 kcol x 32 j, j contiguous in memory
        #pragma unroll
        for (int m = 0; m < 2; m++) {
            const int kc = ukc + 32 * m;
            const size_t o = boff + koffb + (size_t)kc * 64 + jb + 4 * ujq;
            const float4 R = *(const float4*)(srcR + o);
            const float4 I = *(const float4*)(srcI + o);
            const int idx = kc * 40 + 4 * ujq;
            unsigned h0, l0, h1, l1;
            split2(R.x, R.y, h0, l0); split2(R.z, R.w, h1, l1);
            *(uint2*)&UP[0][idx] = make_uint2(h0, h1);
            *(uint2*)&UP[1][idx] = make_uint2(l0, l1);
            split2(I.x, I.y, h0, l0); split2(I.z, I.w, h1, l1);
            *(uint2*)&UP[2][idx] = make_uint2(h0, h1);
            *(uint2*)&UP[3][idx] = make_uint2(l0, l1);
        }
        __syncthreads();

        sh8 a[2][4], na[2][2], bfr[2][4];
        #pragma unroll
        for (int s = 0; s < 2; s++) {
            const int row = wr * 32 + s * 16 + frow;
            #pragma unroll
            for (int p = 0; p < 4; p++) a[s][p] = ldfrag40(&MP[p][0], row, kg);
            na[s][0] = a[s][2] ^ SGN;
            na[s][1] = a[s][3] ^ SGN;
        }
        #pragma unroll
        for (int s = 0; s < 2; s++) {
            const int row = wc * 32 + s * 16 + frow;
            #pragma unroll
            for (int p = 0; p < 4; p++) bfr[s][p] = ldfrag40(&UP[p][0], row, kg);
        }

        #pragma unroll
        for (int sr = 0; sr < 2; sr++) {
            #pragma unroll
            for (int sc = 0; sc < 2; sc++) {
                f32x4 r = gr[sr][sc], q = gi[sr][sc];
                r = MFMA16(a[sr][0],  bfr[sc][0], r);
                r = MFMA16(a[sr][0],  bfr[sc][1], r);
                r = MFMA16(a[sr][1],  bfr[sc][0], r);
                r = MFMA16(na[sr][0], bfr[sc][2], r);
                r = MFMA16(na[sr][0], bfr[sc][3], r);
                r = MFMA16(na[sr][1], bfr[sc][2], r);
                q = MFMA16(a[sr][0],  bfr[sc][2], q);
                q = MFMA16(a[sr][0],  bfr[sc][3], q);
                q = MFMA16(a[sr][1],  bfr[sc][2], q);
                q = MFMA16(a[sr][2],  bfr[sc][0], q);
                q = MFMA16(a[sr][2],  bfr[sc][1], q);
                q = MFMA16(a[sr][3],  bfr[sc][0], q);
                gr[sr][sc] = r; gi[sr][sc] = q;
            }
        }
        __syncthreads();
    }

    // epilogue: lane holds 4 consecutive i (rows) at one kcol (col) -> float4
    #pragma unroll
    for (int sr = 0; sr < 2; sr++)
        #pragma unroll
        for (int sc = 0; sc < 2; sc++) {
            const int i  = wr * 32 + sr * 16 + 4 * (lane >> 4);
            const int kc = wc * 32 + sc * 16 + (lane & 15);
            const size_t o = boff + koffb + (size_t)kc * 64 + i;
            *(float4*)(dstR + o) = make_float4(gr[sr][sc][0], gr[sr][sc][1],
                                               gr[sr][sc][2], gr[sr][sc][3]);
            *(float4*)(dstI + o) = make_float4(gi[sr][sc][0], gi[sr][sc][1],
                                               gi[sr][sc][2], gi[sr][sc][3]);
        }
}

extern "C" void kernel_launch(void* const* d_in, const int* in_sizes, int n_in,
                              void* d_out, int out_size, void* d_ws, size_t ws_size,
                              hipStream_t stream)
{
    const float* xr  = (const float*)d_in[0];
    const float* xi  = (const float*)d_in[1];
    const float* w0r = (const float*)d_in[2];
    const float* w0i = (const float*)d_in[3];
    const float* w1r = (const float*)d_in[4];
    const float* w1i = (const float*)d_in[5];
    const float* w2r = (const float*)d_in[6];
    const float* w2i = (const float*)d_in[7];
    const float* lt  = (const float*)d_in[8];

    float* outR = (float*)d_out;
    float* outI = outR + (size_t)BATCH * SSIZE;

    float*  wsR = (float*)d_ws;
    float*  wsI = wsR + (size_t)BATCH * SSIZE;
    float*  Gf  = wsI + (size_t)BATCH * SSIZE;
    float2* Mf  = (float2*)(Gf + (size_t)BATCH * 128 * 128 * 2);

    // Partial slabs span the contiguous DEAD R+I pair (64 MB each):
    //  mode 0: outR..outI (mix128-mode0 writes both only after reduce)
    //  mode 1: wsR..wsI   (mix128-mode1 writes both only after reduce)
    //  mode 2: outR..outI (mix64 writes both only after reduce)
    // NS=32 (d=128): 8b*32*128*128*2*4B = 33.6MB < 64MB. grid 3*32*8 = 768 = 3/CU.
    // NS=128 (d=64): 8b*128*64*64*2*4B  = 33.6MB < 64MB. grid 128*8 = 1024 = 4/CU.

    // ---------------- mode 0: d=128, SI=8192, KL2=13
    gram_mfma_kernel<8192, 13, 0><<<dim3(3, 32, BATCH), 256, 0, stream>>>(xr, xi, outR, 256);
    reduce_kernel<32, 8192><<<dim3(256), 256, 0, stream>>>((const float4*)outR, (float4*)Gf);
    score_kernel<<<dim3(128, BATCH), 128, 0, stream>>>(Gf, w0r, w0i, lt, Mf, 128);
    mix128_mfma_kernel<8192, 13, 0><<<dim3(128, 2, BATCH), 256, 0, stream>>>(xr, xi, Mf, outR, outI);

    // ---------------- mode 1: d=128, SI=64, KL2=6, SKH=8192
    gram_mfma_kernel<64, 6, 8192><<<dim3(3, 32, BATCH), 256, 0, stream>>>(outR, outI, wsR, 256);
    reduce_kernel<32, 8192><<<dim3(256), 256, 0, stream>>>((const float4*)wsR, (float4*)Gf);
    score_kernel<<<dim3(128, BATCH), 128, 0, stream>>>(Gf, w1r, w1i, lt, Mf, 128);
    mix128_mfma_kernel<64, 6, 8192><<<dim3(128, 2, BATCH), 256, 0, stream>>>(outR, outI, Mf, wsR, wsI);

    // ---------------- mode 2: d=64, SI=1, k: (k&127)*64 + (k>>7)*8192
    gram64_mfma_kernel<<<dim3(128, BATCH), 256, 0, stream>>>(wsR, wsI, outR, 128);
    reduce_kernel<128, 2048><<<dim3(64), 256, 0, stream>>>((const float4*)outR, (float4*)Gf);
    score_kernel<<<dim3(64, BATCH), 64, 0, stream>>>(Gf, w2r, w2i, lt, Mf, 64);
    mix64_mfma_kernel<<<dim3(256, BATCH), 256, 0, stream>>>(wsR, wsI, Mf, outR, outI);
}

// Round 8
// 421.995 us; speedup vs baseline: 2.2118x; 1.0112x over previous
//
#include <hip/hip_runtime.h>
#include <math.h>

#define BATCH 8
#define SSIZE 1048576   // 128*128*64

// R14: mix kernels de-VALU'd (R7 counters: mix128 58.7us x2, VALUBusy 31%,
// MfmaUtil 16%, Occ 36% -- M re-split from f32 in every k-tile block =
// 16K redundant split2/block). Changes: (1) score_kernel emits M as 4
// packed bf16 planes (MrH/MrL/MiH/MiL) -> mix M-staging is a pure uint4
// copy; (2) mix lb(256,3)->(256,4): 4x40960B LDS = exactly the 160KB pool.
// gram/gram64/reduce unchanged (R11 body, measured 426.7us, absmax 3.05e-5).

typedef short sh8 __attribute__((ext_vector_type(8)));
typedef float f32x4 __attribute__((ext_vector_type(4)));

#define MFMA16(a, b, c) __builtin_amdgcn_mfma_f32_16x16x32_bf16((a), (b), (c), 0, 0, 0)

__device__ __forceinline__ unsigned short bf_rne(float x) {
    unsigned u = __float_as_uint(x);
    unsigned r = u + 0x7fffu + ((u >> 16) & 1u);
    return (unsigned short)(r >> 16);
}

// split x into hi + lo bf16 (both RNE)
__device__ __forceinline__ void split1(float x, unsigned short &h, unsigned short &l) {
    h = bf_rne(x);
    float hf = __uint_as_float((unsigned)h << 16);
    l = bf_rne(x - hf);
}

// split two floats, pack hi pair / lo pair as u32 (a in low 16, b in high)
__device__ __forceinline__ void split2(float a, float b, unsigned &hh, unsigned &ll) {
    unsigned short ha = bf_rne(a), hb = bf_rne(b);
    hh = (unsigned)ha | ((unsigned)hb << 16);
    float ra = a - __uint_as_float((unsigned)ha << 16);
    float rb = b - __uint_as_float((unsigned)hb << 16);
    ll = (unsigned)bf_rne(ra) | ((unsigned)bf_rne(rb) << 16);
}

__device__ __forceinline__ float f4c(const float4 &v, int c) {
    return c == 0 ? v.x : c == 1 ? v.y : c == 2 ? v.z : v.w;
}

// fragment load, pitch-32 planes with XOR swizzle (gram kernels, proven)
__device__ __forceinline__ sh8 ldfrag(const unsigned short *pl, int row, int kg) {
    const int idx = (row * 32 + kg * 8) ^ ((row & 3) << 3);
    return *(const sh8 *)(pl + idx);
}

// fragment load, pitch-40 planes, no swizzle (mix kernels; bank-optimal)
__device__ __forceinline__ sh8 ldfrag40(const unsigned short *pl, int row, int kg) {
    return *(const sh8 *)(pl + row * 40 + kg * 8);
}

// ---------------- partial-slab reduce: out[b][r] = sum_s in[b][s][r] --------
template<int NS, int PERB>   // PERB in float4 units
__global__ __launch_bounds__(256)
void reduce_kernel(const float4* __restrict__ in, float4* __restrict__ out) {
    const int gid = blockIdx.x * blockDim.x + threadIdx.x;
    const int b = gid / PERB, r = gid - b * PERB;
    const float4* p = in + (size_t)b * NS * PERB + r;
    float4 a = p[0];
    #pragma unroll 8
    for (int s = 1; s < NS; s++) {
        const float4 v = p[(size_t)s * PERB];
        a.x += v.x; a.y += v.y; a.z += v.z; a.w += v.w;
    }
    out[gid] = a;
}

// =====================================================================
// gram_mfma (modes 0/1, d=128): G = u u^T, symmetric. (R11 body, proven.)
// =====================================================================
template<int SI_, int KL2_, int SKH_>
__global__ __launch_bounds__(256, 3)
void gram_mfma_kernel(const float* __restrict__ srcR, const float* __restrict__ srcI,
                      float* __restrict__ Gp, int kPerBlock)
{
    const int tile = blockIdx.x;             // 0,1,2
    const int it = (tile == 2) ? 64 : 0;
    const int jt = (tile == 0) ? 0 : 64;
    const bool diag = (it == jt);
    const int b  = blockIdx.z;
    const int k0 = blockIdx.y * kPerBlock;

    const int t    = threadIdx.x;
    const int lane = t & 63;
    const int wave = t >> 6;          // 0..3
    const int wr = wave & 1, wc = wave >> 1;

    __shared__ unsigned short SA[4][2048];   // planes rH,rL,iH,iL  [64 rows][32 k]
    __shared__ unsigned short SB[4][2048];

    const sh8 SGN = {(short)0x8000, (short)0x8000, (short)0x8000, (short)0x8000,
                     (short)0x8000, (short)0x8000, (short)0x8000, (short)0x8000};

    f32x4 gr[2][2], gi[2][2];
    const f32x4 z4 = {0.f, 0.f, 0.f, 0.f};
    #pragma unroll
    for (int x = 0; x < 2; x++)
        #pragma unroll
        for (int y = 0; y < 2; y++) { gr[x][y] = z4; gi[x][y] = z4; }

    const size_t boff = (size_t)b * SSIZE;
    const int nT = kPerBlock >> 5;

    const int kq   = t & 7;
    const int row2 = t >> 3;

    const int frow = lane & 15;
    const int kg   = lane >> 4;

    #define GADDR(ii, k) (boff + (size_t)(ii) * SI_ + \
        (size_t)((k) >> KL2_) * SKH_ + (size_t)((k) & ((1 << KL2_) - 1)))

    for (int kt = 0; kt < nT; kt++) {
        const int kb = k0 + kt * 32;
        #pragma unroll
        for (int m = 0; m < 2; m++) {
            const int row = row2 + 32 * m;
            const int idx = (row * 32 + kq * 4) ^ ((row & 3) << 3);
            {
                const size_t off = GADDR(it + row, kb + kq * 4);
                const float4 R = *(const float4*)(srcR + off);
                const float4 I = *(const float4*)(srcI + off);
                ushort4 rh, rl, ih, il;
                split1(R.x, rh.x, rl.x); split1(R.y, rh.y, rl.y);
                split1(R.z, rh.z, rl.z); split1(R.w, rh.w, rl.w);
                split1(I.x, ih.x, il.x); split1(I.y, ih.y, il.y);
                split1(I.z, ih.z, il.z); split1(I.w, ih.w, il.w);
                *(ushort4*)&SA[0][idx] = rh;
                *(ushort4*)&SA[1][idx] = rl;
                *(ushort4*)&SA[2][idx] = ih;
                *(ushort4*)&SA[3][idx] = il;
            }
            if (!diag) {
                const size_t off = GADDR(jt + row, kb + kq * 4);
                const float4 R = *(const float4*)(srcR + off);
                const float4 I = *(const float4*)(srcI + off);
                ushort4 rh, rl, ih, il;
                split1(R.x, rh.x, rl.x); split1(R.y, rh.y, rl.y);
                split1(R.z, rh.z, rl.z); split1(R.w, rh.w, rl.w);
                split1(I.x, ih.x, il.x); split1(I.y, ih.y, il.y);
                split1(I.z, ih.z, il.z); split1(I.w, ih.w, il.w);
                *(ushort4*)&SB[0][idx] = rh;
                *(ushort4*)&SB[1][idx] = rl;
                *(ushort4*)&SB[2][idx] = ih;
                *(ushort4*)&SB[3][idx] = il;
            }
        }
        __syncthreads();

        unsigned short (*BP)[2048] = diag ? SA : SB;

        sh8 a[2][4], na[2][2], bfr[2][4];
        #pragma unroll
        for (int s = 0; s < 2; s++) {
            const int row = wr * 32 + s * 16 + frow;
            #pragma unroll
            for (int p = 0; p < 4; p++) a[s][p] = ldfrag(&SA[p][0], row, kg);
            na[s][0] = a[s][2] ^ SGN;
            na[s][1] = a[s][3] ^ SGN;
        }
        #pragma unroll
        for (int s = 0; s < 2; s++) {
            const int row = wc * 32 + s * 16 + frow;
            #pragma unroll
            for (int p = 0; p < 4; p++) bfr[s][p] = ldfrag(&BP[p][0], row, kg);
        }

        #pragma unroll
        for (int sr = 0; sr < 2; sr++) {
            #pragma unroll
            for (int sc = 0; sc < 2; sc++) {
                f32x4 r = gr[sr][sc], q = gi[sr][sc];
                r = MFMA16(a[sr][0],  bfr[sc][0], r);
                r = MFMA16(a[sr][0],  bfr[sc][1], r);
                r = MFMA16(a[sr][1],  bfr[sc][0], r);
                r = MFMA16(na[sr][0], bfr[sc][2], r);
                r = MFMA16(na[sr][0], bfr[sc][3], r);
                r = MFMA16(na[sr][1], bfr[sc][2], r);
                q = MFMA16(a[sr][0],  bfr[sc][2], q);
                q = MFMA16(a[sr][0],  bfr[sc][3], q);
                q = MFMA16(a[sr][1],  bfr[sc][2], q);
                q = MFMA16(a[sr][2],  bfr[sc][0], q);
                q = MFMA16(a[sr][2],  bfr[sc][1], q);
                q = MFMA16(a[sr][3],  bfr[sc][0], q);
                gr[sr][sc] = r; gi[sr][sc] = q;
            }
        }
        __syncthreads();
    }
    #undef GADDR

    float* Gb = Gp + ((size_t)b * gridDim.y + blockIdx.y) * (128 * 128 * 2);
    const int rb   = (lane >> 4) * 4;
    const int jcol = lane & 15;
    #pragma unroll
    for (int sr = 0; sr < 2; sr++)
        #pragma unroll
        for (int sc = 0; sc < 2; sc++)
            #pragma unroll
            for (int r = 0; r < 4; r++) {
                const int i = it + wr * 32 + sr * 16 + rb + r;
                const int j = jt + wc * 32 + sc * 16 + jcol;
                const float vr = gr[sr][sc][r], vi = gi[sr][sc][r];
                *(float2*)&Gb[(i * 128 + j) * 2] = make_float2(vr, vi);
                if (!diag)
                    *(float2*)&Gb[(j * 128 + i) * 2] = make_float2(vr, vi);
            }
}

// =====================================================================
// gram64_mfma (mode 2, d=64). R11 body, proven.
// =====================================================================
__global__ __launch_bounds__(256, 4)
void gram64_mfma_kernel(const float* __restrict__ srcR, const float* __restrict__ srcI,
                        float* __restrict__ Gp, int kPerBlock)
{
    const int b  = blockIdx.y;
    const int k0 = blockIdx.x * kPerBlock;

    const int t    = threadIdx.x;
    const int lane = t & 63;
    const int wave = t >> 6;
    const int wr = wave & 1, wc = wave >> 1;

    __shared__ unsigned short SA[4][2048];   // planes [64 i][32 k]

    const sh8 SGN = {(short)0x8000, (short)0x8000, (short)0x8000, (short)0x8000,
                     (short)0x8000, (short)0x8000, (short)0x8000, (short)0x8000};

    f32x4 gr[2][2], gi[2][2];
    const f32x4 z4 = {0.f, 0.f, 0.f, 0.f};
    #pragma unroll
    for (int x = 0; x < 2; x++)
        #pragma unroll
        for (int y = 0; y < 2; y++) { gr[x][y] = z4; gi[x][y] = z4; }

    const size_t boff = (size_t)b * SSIZE;
    const int nT = kPerBlock >> 5;

    const int kp = t & 15;        // k = 2kp, 2kp+1 within tile
    const int i0 = (t >> 4) * 4;  // i quad

    const int frow = lane & 15;
    const int kg   = lane >> 4;

    for (int kt = 0; kt < nT; kt++) {
        const int kb = k0 + kt * 32;
        const int ke = kb + 2 * kp;
        const int ko = ke + 1;
        const size_t offE = boff + (size_t)(ke & 127) * 64 + (size_t)(ke >> 7) * 8192 + i0;
        const size_t offO = boff + (size_t)(ko & 127) * 64 + (size_t)(ko >> 7) * 8192 + i0;
        const float4 R0 = *(const float4*)(srcR + offE);
        const float4 I0 = *(const float4*)(srcI + offE);
        const float4 R1 = *(const float4*)(srcR + offO);
        const float4 I1 = *(const float4*)(srcI + offO);
        const int kw = 2 * kp;
        #pragma unroll
        for (int c = 0; c < 4; c++) {
            const int i   = i0 + c;
            const int idx = (i * 32 + kw) ^ ((i & 3) << 3);
            unsigned short h0, l0, h1, l1;
            split1(f4c(R0, c), h0, l0);
            split1(f4c(R1, c), h1, l1);
            *(ushort2*)&SA[0][idx] = make_ushort2(h0, h1);
            *(ushort2*)&SA[1][idx] = make_ushort2(l0, l1);
            split1(f4c(I0, c), h0, l0);
            split1(f4c(I1, c), h1, l1);
            *(ushort2*)&SA[2][idx] = make_ushort2(h0, h1);
            *(ushort2*)&SA[3][idx] = make_ushort2(l0, l1);
        }
        __syncthreads();

        sh8 a[2][4], na[2][2], bfr[2][4];
        #pragma unroll
        for (int s = 0; s < 2; s++) {
            const int row = wr * 32 + s * 16 + frow;
            #pragma unroll
            for (int p = 0; p < 4; p++) a[s][p] = ldfrag(&SA[p][0], row, kg);
            na[s][0] = a[s][2] ^ SGN;
            na[s][1] = a[s][3] ^ SGN;
        }
        #pragma unroll
        for (int s = 0; s < 2; s++) {
            const int row = wc * 32 + s * 16 + frow;
            #pragma unroll
            for (int p = 0; p < 4; p++) bfr[s][p] = ldfrag(&SA[p][0], row, kg);
        }

        #pragma unroll
        for (int sr = 0; sr < 2; sr++) {
            #pragma unroll
            for (int sc = 0; sc < 2; sc++) {
                f32x4 r = gr[sr][sc], q = gi[sr][sc];
                r = MFMA16(a[sr][0],  bfr[sc][0], r);
                r = MFMA16(a[sr][0],  bfr[sc][1], r);
                r = MFMA16(a[sr][1],  bfr[sc][0], r);
                r = MFMA16(na[sr][0], bfr[sc][2], r);
                r = MFMA16(na[sr][0], bfr[sc][3], r);
                r = MFMA16(na[sr][1], bfr[sc][2], r);
                q = MFMA16(a[sr][0],  bfr[sc][2], q);
                q = MFMA16(a[sr][0],  bfr[sc][3], q);
                q = MFMA16(a[sr][1],  bfr[sc][2], q);
                q = MFMA16(a[sr][2],  bfr[sc][0], q);
                q = MFMA16(a[sr][2],  bfr[sc][1], q);
                q = MFMA16(a[sr][3],  bfr[sc][0], q);
                gr[sr][sc] = r; gi[sr][sc] = q;
            }
        }
        __syncthreads();
    }

    float* Gb = Gp + ((size_t)b * gridDim.x + blockIdx.x) * (64 * 64 * 2);
    const int rb   = (lane >> 4) * 4;
    const int jcol = lane & 15;
    #pragma unroll
    for (int sr = 0; sr < 2; sr++)
        #pragma unroll
        for (int sc = 0; sc < 2; sc++)
            #pragma unroll
            for (int r = 0; r < 4; r++) {
                const int i = wr * 32 + sr * 16 + rb + r;
                const int j = wc * 32 + sc * 16 + jcol;
                *(float2*)&Gb[(i * 64 + j) * 2] = make_float2(gr[sr][sc][r], gi[sr][sc][r]);
            }
}

// ---------------- score/softmax/phase -> routing matrix M ----------------
// R14: writes M as 4 packed bf16 planes [b][p][d*d]: p=0 MrH, 1 MrL, 2 MiH, 3 MiL
__global__ __launch_bounds__(128)
void score_kernel(const float* __restrict__ G,
                  const float* __restrict__ Wre, const float* __restrict__ Wim,
                  const float* __restrict__ log_tau,
                  unsigned short* __restrict__ Mout, int d)
{
    const int b = blockIdx.y;
    const int i = blockIdx.x;
    const int j = threadIdx.x;

    const float2* Gb = (const float2*)G + (size_t)b * d * d;

    float sre = 0.f, sim = 0.f;
    for (int l = 0; l < d; l++) {
        float wr = Wre[i * d + l];
        float wi = Wim[i * d + l];
        float2 g = Gb[l * d + j];
        sre = fmaf(wr, g.x, sre);
        sre = fmaf(-wi, g.y, sre);
        sim = fmaf(wr, g.y, sim);
        sim = fmaf(wi, g.x, sim);
    }

    float mag = sqrtf(sre * sre + sim * sim);
    float tau = fmaxf(expf(log_tau[0]), 1e-8f);
    float scale = tau * sqrtf((float)SSIZE / (float)d);
    float mval = mag / scale;

    __shared__ float red[128];
    red[j] = mval;
    __syncthreads();
    for (int s = d >> 1; s > 0; s >>= 1) {
        if (j < s) red[j] = fmaxf(red[j], red[j + s]);
        __syncthreads();
    }
    float mx = red[0];
    __syncthreads();
    float e = expf(mval - mx);
    red[j] = e;
    __syncthreads();
    for (int s = d >> 1; s > 0; s >>= 1) {
        if (j < s) red[j] += red[j + s];
        __syncthreads();
    }
    float routing = e / red[0];

    float safe = fmaxf(mag, 1e-8f);
    float pre, pim;
    if (mag > 1e-8f) { pre = sre / safe; pim = sim / safe; }
    else             { pre = 1.f;       pim = 0.f; }

    const float mr = routing * pre;
    const float mi = routing * pim;
    const size_t dd = (size_t)d * d;
    unsigned short h, l;
    split1(mr, h, l);
    Mout[((size_t)b * 4 + 0) * dd + i * d + j] = h;
    Mout[((size_t)b * 4 + 1) * dd + i * d + j] = l;
    split1(mi, h, l);
    Mout[((size_t)b * 4 + 2) * dd + i * d + j] = h;
    Mout[((size_t)b * 4 + 3) * dd + i * d + j] = l;
}

// =====================================================================
// mix128_mfma (modes 0/1, d=128). R14: M planes pre-split (copy-only
// staging), lb(256,4) -> 4 blocks/CU (4x40KB = full 160KB LDS pool).
// =====================================================================
template<int SI_, int KL2_, int SKH_>
__global__ __launch_bounds__(256, 4)
void mix128_mfma_kernel(const float* __restrict__ srcR, const float* __restrict__ srcI,
                        const unsigned short* __restrict__ Mp,
                        float* __restrict__ dstR, float* __restrict__ dstI)
{
    const int kb0 = blockIdx.x << 6;   // 64-wide k tile
    const int it  = blockIdx.y << 6;   // 64-wide i tile
    const int b   = blockIdx.z;

    const int t    = threadIdx.x;
    const int lane = t & 63;
    const int wave = t >> 6;
    const int wr = wave & 1, wc = wave >> 1;   // wr: k half, wc: i half

    __shared__ unsigned short UP[4][2560];   // u^T planes [kcol 0..63][j 0..31], pitch 40
    __shared__ unsigned short MP[4][2560];   // M   planes [i    0..63][j 0..31], pitch 40

    const sh8 SGN = {(short)0x8000, (short)0x8000, (short)0x8000, (short)0x8000,
                     (short)0x8000, (short)0x8000, (short)0x8000, (short)0x8000};

    f32x4 gr[2][2], gi[2][2];     // [sr: k-sub][sc: i-sub]
    const f32x4 z4 = {0.f, 0.f, 0.f, 0.f};
    #pragma unroll
    for (int x = 0; x < 2; x++)
        #pragma unroll
        for (int y = 0; y < 2; y++) { gr[x][y] = z4; gi[x][y] = z4; }

    const size_t boff = (size_t)b * SSIZE;
    const unsigned short* Mb = Mp + (size_t)b * 4 * 16384;   // 4 planes of 128*128

    #define GADDR(jj, k) (boff + (size_t)(jj) * SI_ + \
        (size_t)((k) >> KL2_) * SKH_ + (size_t)((k) & ((1 << KL2_) - 1)))

    // staging maps
    const int ujp = t & 15;        // j pair: j0 = 2*ujp
    const int uq  = t >> 4;        // k quad: kc0 = 4*uq
    const int mi  = t >> 2;        // i row for M
    const int mj8 = (t & 3) * 8;   // j octet for M

    const int frow = lane & 15;
    const int kg   = lane >> 4;

    for (int jt = 0; jt < 4; jt++) {
        const int jb = jt * 32;
        // ---- stage M: pure copy of pre-split planes (16B loads/stores)
        {
            const int src = (it + mi) * 128 + jb + mj8;
            const int idx = mi * 40 + mj8;
            #pragma unroll
            for (int p = 0; p < 4; p++)
                *(uint4*)&MP[p][idx] = *(const uint4*)&Mb[p * 16384 + src];
        }
        // ---- stage u^T: 64 kcol x 32 j, uint stores (split in-kernel)
        {
            const int j0 = 2 * ujp;
            const size_t o0 = GADDR(jb + j0,     kb0 + 4 * uq);
            const size_t o1 = GADDR(jb + j0 + 1, kb0 + 4 * uq);
            const float4 R0 = *(const float4*)(srcR + o0);
            const float4 R1 = *(const float4*)(srcR + o1);
            const float4 I0 = *(const float4*)(srcI + o0);
            const float4 I1 = *(const float4*)(srcI + o1);
            #pragma unroll
            for (int c = 0; c < 4; c++) {
                const int kc  = 4 * uq + c;
                const int idx = kc * 40 + j0;
                unsigned hh, ll;
                split2(f4c(R0, c), f4c(R1, c), hh, ll);
                *(unsigned*)&UP[0][idx] = hh;
                *(unsigned*)&UP[1][idx] = ll;
                split2(f4c(I0, c), f4c(I1, c), hh, ll);
                *(unsigned*)&UP[2][idx] = hh;
                *(unsigned*)&UP[3][idx] = ll;
            }
        }
        __syncthreads();

        sh8 a[2][4], na[2][2], bfr[2][4];
        #pragma unroll
        for (int s = 0; s < 2; s++) {
            const int row = wr * 32 + s * 16 + frow;
            #pragma unroll
            for (int p = 0; p < 4; p++) a[s][p] = ldfrag40(&UP[p][0], row, kg);
            na[s][0] = a[s][2] ^ SGN;
            na[s][1] = a[s][3] ^ SGN;
        }
        #pragma unroll
        for (int s = 0; s < 2; s++) {
            const int row = wc * 32 + s * 16 + frow;
            #pragma unroll
            for (int p = 0; p < 4; p++) bfr[s][p] = ldfrag40(&MP[p][0], row, kg);
        }

        #pragma unroll
        for (int sr = 0; sr < 2; sr++) {
            #pragma unroll
            for (int sc = 0; sc < 2; sc++) {
                f32x4 r = gr[sr][sc], q = gi[sr][sc];
                // Dr = Ur*Mr - Ui*Mi (split HH+HL+LH)
                r = MFMA16(a[sr][0],  bfr[sc][0], r);
                r = MFMA16(a[sr][0],  bfr[sc][1], r);
                r = MFMA16(a[sr][1],  bfr[sc][0], r);
                r = MFMA16(na[sr][0], bfr[sc][2], r);
                r = MFMA16(na[sr][0], bfr[sc][3], r);
                r = MFMA16(na[sr][1], bfr[sc][2], r);
                // Di = Ur*Mi + Ui*Mr
                q = MFMA16(a[sr][0],  bfr[sc][2], q);
                q = MFMA16(a[sr][0],  bfr[sc][3], q);
                q = MFMA16(a[sr][1],  bfr[sc][2], q);
                q = MFMA16(a[sr][2],  bfr[sc][0], q);
                q = MFMA16(a[sr][2],  bfr[sc][1], q);
                q = MFMA16(a[sr][3],  bfr[sc][0], q);
                gr[sr][sc] = r; gi[sr][sc] = q;
            }
        }
        __syncthreads();
    }

    // epilogue: lane holds 4 consecutive k (rows) at one i (col) -> float4
    #pragma unroll
    for (int sr = 0; sr < 2; sr++)
        #pragma unroll
        for (int sc = 0; sc < 2; sc++) {
            const int k = kb0 + wr * 32 + sr * 16 + 4 * (lane >> 4);
            const int i = it  + wc * 32 + sc * 16 + (lane & 15);
            const size_t o = boff + (size_t)i * SI_ +
                (size_t)(k >> KL2_) * SKH_ + (size_t)(k & ((1 << KL2_) - 1));
            *(float4*)(dstR + o) = make_float4(gr[sr][sc][0], gr[sr][sc][1],
                                               gr[sr][sc][2], gr[sr][sc][3]);
            *(float4*)(dstI + o) = make_float4(gi[sr][sc][0], gi[sr][sc][1],
                                               gi[sr][sc][2], gi[sr][sc][3]);
        }
    #undef GADDR
}

// =====================================================================
// mix64_mfma (mode 2, d=64). R14: M planes pre-split, lb(256,4).
// =====================================================================
__global__ __launch_bounds__(256, 4)
void mix64_mfma_kernel(const float* __restrict__ srcR, const float* __restrict__ srcI,
                       const unsigned short* __restrict__ Mp,
                       float* __restrict__ dstR, float* __restrict__ dstI)
{
    const int kb0 = blockIdx.x << 6;   // 64-wide k tile
    const int b   = blockIdx.y;

    const int t    = threadIdx.x;
    const int lane = t & 63;
    const int wave = t >> 6;
    const int wr = wave & 1, wc = wave >> 1;   // wr: i half, wc: k half

    __shared__ unsigned short UP[4][2560];   // u^T planes [kcol][j 0..31], pitch 40
    __shared__ unsigned short MP[4][2560];   // M   planes [i   ][j 0..31], pitch 40

    const sh8 SGN = {(short)0x8000, (short)0x8000, (short)0x8000, (short)0x8000,
                     (short)0x8000, (short)0x8000, (short)0x8000, (short)0x8000};

    f32x4 gr[2][2], gi[2][2];     // [sr: i-sub][sc: k-sub]
    const f32x4 z4 = {0.f, 0.f, 0.f, 0.f};
    #pragma unroll
    for (int x = 0; x < 2; x++)
        #pragma unroll
        for (int y = 0; y < 2; y++) { gr[x][y] = z4; gi[x][y] = z4; }

    const size_t boff  = (size_t)b * SSIZE;
    const unsigned short* Mb = Mp + (size_t)b * 4 * 4096;    // 4 planes of 64*64
    const size_t koffb = (size_t)(kb0 & 127) * 64 + (size_t)(kb0 >> 7) * 8192;

    // staging maps
    const int mi  = t >> 2;        // i row for M
    const int mj8 = (t & 3) * 8;   // j octet for M
    const int ujq = t & 7;         // j quad: j0 = 4*ujq
    const int ukc = t >> 3;        // kcol 0..31 (+32 second item)

    const int frow = lane & 15;
    const int kg   = lane >> 4;

    for (int jt = 0; jt < 2; jt++) {
        const int jb = jt * 32;
        // ---- stage M: pure copy of pre-split planes
        {
            const int src = mi * 64 + jb + mj8;
            const int idx = mi * 40 + mj8;
            #pragma unroll
            for (int p = 0; p < 4; p++)
                *(uint4*)&MP[p][idx] = *(const uint4*)&Mb[p * 4096 + src];
        }
        // ---- stage u^T: 64 kcol x 32 j, j contiguous in memory
        #pragma unroll
        for (int m = 0; m < 2; m++) {
            const int kc = ukc + 32 * m;
            const size_t o = boff + koffb + (size_t)kc * 64 + jb + 4 * ujq;
            const float4 R = *(const float4*)(srcR + o);
            const float4 I = *(const float4*)(srcI + o);
            const int idx = kc * 40 + 4 * ujq;
            unsigned h0, l0, h1, l1;
            split2(R.x, R.y, h0, l0); split2(R.z, R.w, h1, l1);
            *(uint2*)&UP[0][idx] = make_uint2(h0, h1);
            *(uint2*)&UP[1][idx] = make_uint2(l0, l1);
            split2(I.x, I.y, h0, l0); split2(I.z, I.w, h1, l1);
            *(uint2*)&UP[2][idx] = make_uint2(h0, h1);
            *(uint2*)&UP[3][idx] = make_uint2(l0, l1);
        }
        __syncthreads();

        sh8 a[2][4], na[2][2], bfr[2][4];
        #pragma unroll
        for (int s = 0; s < 2; s++) {
            const int row = wr * 32 + s * 16 + frow;
            #pragma unroll
            for (int p = 0; p < 4; p++) a[s][p] = ldfrag40(&MP[p][0], row, kg);
            na[s][0] = a[s][2] ^ SGN;
            na[s][1] = a[s][3] ^ SGN;
        }
        #pragma unroll
        for (int s = 0; s < 2; s++) {
            const int row = wc * 32 + s * 16 + frow;
            #pragma unroll
            for (int p = 0; p < 4; p++) bfr[s][p] = ldfrag40(&UP[p][0], row, kg);
        }

        #pragma unroll
        for (int sr = 0; sr < 2; sr++) {
            #pragma unroll
            for (int sc = 0; sc < 2; sc++) {
                f32x4 r = gr[sr][sc], q = gi[sr][sc];
                r = MFMA16(a[sr][0],  bfr[sc][0], r);
                r = MFMA16(a[sr][0],  bfr[sc][1], r);
                r = MFMA16(a[sr][1],  bfr[sc][0], r);
                r = MFMA16(na[sr][0], bfr[sc][2], r);
                r = MFMA16(na[sr][0], bfr[sc][3], r);
                r = MFMA16(na[sr][1], bfr[sc][2], r);
                q = MFMA16(a[sr][0],  bfr[sc][2], q);
                q = MFMA16(a[sr][0],  bfr[sc][3], q);
                q = MFMA16(a[sr][1],  bfr[sc][2], q);
                q = MFMA16(a[sr][2],  bfr[sc][0], q);
                q = MFMA16(a[sr][2],  bfr[sc][1], q);
                q = MFMA16(a[sr][3],  bfr[sc][0], q);
                gr[sr][sc] = r; gi[sr][sc] = q;
            }
        }
        __syncthreads();
    }

    // epilogue: lane holds 4 consecutive i (rows) at one kcol (col) -> float4
    #pragma unroll
    for (int sr = 0; sr < 2; sr++)
        #pragma unroll
        for (int sc = 0; sc < 2; sc++) {
            const int i  = wr * 32 + sr * 16 + 4 * (lane >> 4);
            const int kc = wc * 32 + sc * 16 + (lane & 15);
            const size_t o = boff + koffb + (size_t)kc * 64 + i;
            *(float4*)(dstR + o) = make_float4(gr[sr][sc][0], gr[sr][sc][1],
                                               gr[sr][sc][2], gr[sr][sc][3]);
            *(float4*)(dstI + o) = make_float4(gi[sr][sc][0], gi[sr][sc][1],
                                               gi[sr][sc][2], gi[sr][sc][3]);
        }
}

extern "C" void kernel_launch(void* const* d_in, const int* in_sizes, int n_in,
                              void* d_out, int out_size, void* d_ws, size_t ws_size,
                              hipStream_t stream)
{
    const float* xr  = (const float*)d_in[0];
    const float* xi  = (const float*)d_in[1];
    const float* w0r = (const float*)d_in[2];
    const float* w0i = (const float*)d_in[3];
    const float* w1r = (const float*)d_in[4];
    const float* w1i = (const float*)d_in[5];
    const float* w2r = (const float*)d_in[6];
    const float* w2i = (const float*)d_in[7];
    const float* lt  = (const float*)d_in[8];

    float* outR = (float*)d_out;
    float* outI = outR + (size_t)BATCH * SSIZE;

    float*  wsR = (float*)d_ws;
    float*  wsI = wsR + (size_t)BATCH * SSIZE;
    float*  Gf  = wsI + (size_t)BATCH * SSIZE;
    // M planes: [b][4][d*d] ushort. d=128: 8*4*16384*2B = 1MB (same as old float2 M).
    unsigned short* Mp = (unsigned short*)(Gf + (size_t)BATCH * 128 * 128 * 2);

    // Partial slabs span the contiguous DEAD R+I pair (64 MB each):
    //  mode 0: outR..outI; mode 1: wsR..wsI; mode 2: outR..outI.
    // NS=32 (d=128): 33.6MB < 64MB. grid 3*32*8 = 768 = 3/CU.
    // NS=128 (d=64): 33.6MB < 64MB. grid 128*8 = 1024 = 4/CU.

    // ---------------- mode 0: d=128, SI=8192, KL2=13
    gram_mfma_kernel<8192, 13, 0><<<dim3(3, 32, BATCH), 256, 0, stream>>>(xr, xi, outR, 256);
    reduce_kernel<32, 8192><<<dim3(256), 256, 0, stream>>>((const float4*)outR, (float4*)Gf);
    score_kernel<<<dim3(128, BATCH), 128, 0, stream>>>(Gf, w0r, w0i, lt, Mp, 128);
    mix128_mfma_kernel<8192, 13, 0><<<dim3(128, 2, BATCH), 256, 0, stream>>>(xr, xi, Mp, outR, outI);

    // ---------------- mode 1: d=128, SI=64, KL2=6, SKH=8192
    gram_mfma_kernel<64, 6, 8192><<<dim3(3, 32, BATCH), 256, 0, stream>>>(outR, outI, wsR, 256);
    reduce_kernel<32, 8192><<<dim3(256), 256, 0, stream>>>((const float4*)wsR, (float4*)Gf);
    score_kernel<<<dim3(128, BATCH), 128, 0, stream>>>(Gf, w1r, w1i, lt, Mp, 128);
    mix128_mfma_kernel<64, 6, 8192><<<dim3(128, 2, BATCH), 256, 0, stream>>>(outR, outI, Mp, wsR, wsI);

    // ---------------- mode 2: d=64, SI=1, k: (k&127)*64 + (k>>7)*8192
    gram64_mfma_kernel<<<dim3(128, BATCH), 256, 0, stream>>>(wsR, wsI, outR, 128);
    reduce_kernel<128, 2048><<<dim3(64), 256, 0, stream>>>((const float4*)outR, (float4*)Gf);
    score_kernel<<<dim3(64, BATCH), 64, 0, stream>>>(Gf, w2r, w2i, lt, Mp, 64);
    mix64_mfma_kernel<<<dim3(256, BATCH), 256, 0, stream>>>(wsR, wsI, Mp, outR, outI);
}